// Round 3
// baseline (8598.486 us; speedup 1.0000x reference)
//
#include <hip/hip_runtime.h>
#include <stdint.h>
#include <math.h>

#define NCLS 80
#define CINCH 256
#define KTOT 2304

static constexpr int LH[5]   = {100,50,25,13,7};
static constexpr int LW[5]   = {152,76,38,19,10};
static constexpr int LHW[5]  = {15200,3800,950,247,70};
static constexpr int LCUM[5] = {0,15200,19000,19950,20197};
static constexpr int TOTHW   = 20267;
static constexpr int LSTR[5] = {8,16,32,64,128};
static constexpr int CPX128[6] = {0,238,298,313,317,319};   // 128-px conv blocks per level (N=2*HW)
static constexpr int CPX64[6]  = {0,475,594,624,632,635};   // 64-px head blocks per level
#define NPXB128 319
#define NPXB64  635

struct ConvArgs {
  const float* in[10];   // [tower*5 + level] input base (per-level [b][c][hw] layout)
  const float* w[2];     // per-tower weight base [Cout][2304]
  const float* b[2];     // per-tower bias
  float* out[2];         // per-tower output act base (MODE0) / scores base in out[0] (MODE1)
  const float* ctrp;     // MODE1 only
  int nt;                // towers in this dispatch (1 or 2)
};

// ---------------- helpers ----------------
__device__ __forceinline__ void lds_hist_add(uint32_t* h, uint32_t bucket) {
  unsigned long long act = __ballot(1);
  int lane = (int)(threadIdx.x & 63u);
  int leader = __ffsll(act) - 1;
  uint32_t lb = (uint32_t)__shfl((int)bucket, leader, 64);
  unsigned long long same = __ballot(bucket == lb);
  if (same == act) {
    if (lane == leader) atomicAdd(&h[bucket], (uint32_t)__popcll(act));
  } else {
    atomicAdd(&h[bucket], 1u);
  }
}

__device__ __forceinline__ uint32_t wave_append_pos(uint32_t* ctr) {
  unsigned long long act = __ballot(1);
  int lane = (int)(threadIdx.x & 63u);
  int leader = __ffsll(act) - 1;
  uint32_t cnt  = (uint32_t)__popcll(act);
  uint32_t rank = (uint32_t)__popcll(act & ((1ull << lane) - 1ull));
  uint32_t base = 0;
  if (lane == leader) base = atomicAdd(ctr, cnt);
  base = (uint32_t)__shfl((int)base, leader, 64);
  return base + rank;
}

// ---------------- main conv (implicit GEMM, fp32) ----------------
// MODE 0: tower conv 256->256, bias+ReLU, write act (NCHW per level), 1-2 towers per dispatch
// MODE 1: logits conv 256->80, sigmoid * ctr_prob, threshold, write scores [l][b][cls][hw]
template<int MODE>
__global__ __launch_bounds__(256)
void conv_k(ConvArgs args) {
  __shared__ float sA[2][1024];
  __shared__ float sB[2][1024];
  const int tid = threadIdx.x;
  const int nt = args.nt;
  int bx = blockIdx.x;
  int l = 0;
#pragma unroll
  for (int i = 1; i < 5; i++) if (bx >= nt*CPX128[i]) l = i;
  int r = bx - nt*CPX128[l];
  const int cl = CPX128[l+1] - CPX128[l];
  int t = 0, pxb = r;
  if (nt == 2 && r >= cl) { t = 1; pxb = r - cl; }
  const int H = LH[l], W = LW[l], HW = LHW[l];
  const int N = 2*HW;
  const int px0 = pxb*128;
  const int oc0 = blockIdx.y*128;
  const int Cout = (MODE == 0) ? CINCH : NCLS;
  const size_t lvl = (size_t)(2*CINCH)*LCUM[l];
  const float* inL = args.in[t*5 + l];
  const float* wgt = args.w[t];
  const float* bias = args.b[t];

  const int w_oc = tid >> 1;
  const int w_k4 = (tid & 1)*4;
  const int b_k  = tid >> 5;
  const int b_px = (tid & 31)*4;

  int lb[4], lhh[4], lww[4]; int lval[4];
#pragma unroll
  for (int i = 0; i < 4; i++) {
    int px = px0 + b_px + i;
    lval[i] = (px < N);
    int pxc = lval[i] ? px : 0;
    int bb = pxc / HW; int hw = pxc - bb*HW;
    int hh = hw / W;
    lb[i] = bb; lhh[i] = hh; lww[i] = hw - hh*W;
  }
  const bool wv = (oc0 + w_oc) < Cout;
  const float* wrow = wgt + (size_t)(oc0 + w_oc)*KTOT + w_k4;

  const int ty = tid >> 4, tx = tid & 15;

  float acc[8][8];
#pragma unroll
  for (int rr = 0; rr < 8; rr++)
#pragma unroll
    for (int c = 0; c < 8; c++) acc[rr][c] = 0.f;

  float4 wr; float br[4];
  auto load = [&](int k0) {
    wr = wv ? *reinterpret_cast<const float4*>(wrow + k0) : make_float4(0.f,0.f,0.f,0.f);
    int k = k0 + b_k;
    int c = k/9; int rk = k - c*9;
    int r3 = rk/3;
    int dh = r3 - 1, dw = (rk - r3*3) - 1;
    const float* cb = inL + (size_t)c*HW;
#pragma unroll
    for (int i = 0; i < 4; i++) {
      int ih = lhh[i] + dh, iw = lww[i] + dw;
      bool ok = lval[i] && ((unsigned)ih < (unsigned)H) && ((unsigned)iw < (unsigned)W);
      br[i] = ok ? cb[(size_t)lb[i]*CINCH*HW + ih*W + iw] : 0.f;
    }
  };
  auto stash = [&](int buf) {
    sA[buf][(w_k4+0)*128 + w_oc] = wr.x;
    sA[buf][(w_k4+1)*128 + w_oc] = wr.y;
    sA[buf][(w_k4+2)*128 + w_oc] = wr.z;
    sA[buf][(w_k4+3)*128 + w_oc] = wr.w;
    *reinterpret_cast<float4*>(&sB[buf][b_k*128 + b_px]) = make_float4(br[0],br[1],br[2],br[3]);
  };
  auto compute = [&](int buf) {
#pragma unroll
    for (int kk = 0; kk < 8; kk++) {
      const float4 a0 = *reinterpret_cast<const float4*>(&sA[buf][kk*128 + ty*4]);
      const float4 a1 = *reinterpret_cast<const float4*>(&sA[buf][kk*128 + 64 + ty*4]);
      const float4 b0 = *reinterpret_cast<const float4*>(&sB[buf][kk*128 + tx*4]);
      const float4 b1 = *reinterpret_cast<const float4*>(&sB[buf][kk*128 + 64 + tx*4]);
      const float av[8] = {a0.x,a0.y,a0.z,a0.w,a1.x,a1.y,a1.z,a1.w};
      const float bw[8] = {b0.x,b0.y,b0.z,b0.w,b1.x,b1.y,b1.z,b1.w};
#pragma unroll
      for (int rr = 0; rr < 8; rr++)
#pragma unroll
        for (int c = 0; c < 8; c++) acc[rr][c] = fmaf(av[rr], bw[c], acc[rr][c]);
    }
  };

  load(0); stash(0);
  __syncthreads();
  for (int k0 = 0; k0 < KTOT; k0 += 8) {
    const int cur = (k0 >> 3) & 1;
    const bool more = (k0 + 8) < KTOT;
    if (more) load(k0 + 8);
    compute(cur);
    if (more) stash(cur ^ 1);
    __syncthreads();
  }

#pragma unroll
  for (int ch = 0; ch < 2; ch++)
#pragma unroll
  for (int ci = 0; ci < 4; ci++) {
    int px = px0 + ch*64 + tx*4 + ci;
    if (px >= N) continue;
    int bb = px / HW; int hw = px - bb*HW;
    if (MODE == 0) {
      float* ob = args.out[t] + lvl + (size_t)bb*CINCH*HW + hw;
#pragma unroll
      for (int rh = 0; rh < 2; rh++)
#pragma unroll
      for (int ri = 0; ri < 4; ri++) {
        int oc = oc0 + rh*64 + ty*4 + ri;
        float v = acc[rh*4+ri][ch*4+ci] + bias[oc];
        ob[(size_t)oc*HW] = fmaxf(v, 0.f);
      }
    } else {
      float cp = args.ctrp[2*LCUM[l] + bb*HW + hw];
      float* ob = args.out[0] + (size_t)NCLS*(2*LCUM[l] + bb*HW) + hw;
#pragma unroll
      for (int rh = 0; rh < 2; rh++)
#pragma unroll
      for (int ri = 0; ri < 4; ri++) {
        int oc = oc0 + rh*64 + ty*4 + ri;
        if (oc < NCLS) {
          float lg = acc[rh*4+ri][ch*4+ci] + bias[oc];
          float pc = 1.0f/(1.0f + expf(-lg));
          float s = pc * cp;
          s = (s > 0.05f) ? s : 0.f;
          ob[(size_t)oc*HW] = s;
        }
      }
    }
  }
}

// ---------------- ctr + reg head (256 -> 5) ----------------
__global__ __launch_bounds__(256)
void k_head(const float* __restrict__ act, const float* __restrict__ ctw,
            const float* __restrict__ ctb, const float* __restrict__ pdw,
            const float* __restrict__ pdb, const float* __restrict__ scl,
            float* __restrict__ ctrp, float* __restrict__ regb) {
  int bx = blockIdx.x; int l = 0;
#pragma unroll
  for (int i = 1; i < 5; i++) if (bx >= CPX64[i]) l = i;
  const int lblk = bx - CPX64[l];
  const int H = LH[l], W = LW[l], HW = LHW[l]; const int N = 2*HW;
  const int p = threadIdx.x & 63;
  const int q = threadIdx.x >> 6;
  const int px = lblk*64 + p;
  float a0 = 0.f, a1 = 0.f, a2 = 0.f, a3 = 0.f, a4 = 0.f;
  int bb = 0, hw = 0, hh = 0, ww = 0;
  const bool ok = (px < N);
  if (ok) {
    bb = px / HW; hw = px - bb*HW; hh = hw / W; ww = hw - hh*W;
    const float* ab = act + (size_t)(2*CINCH)*LCUM[l] + (size_t)bb*CINCH*HW;
    for (int c = q*64; c < q*64 + 64; ++c) {
      const float* xb = ab + (size_t)c*HW;
      const int k0 = c*9;
#pragma unroll
      for (int r = 0; r < 9; r++) {
        int dh = r/3 - 1, dw = r%3 - 1;
        int ih = hh + dh, iw = ww + dw;
        float xv = (((unsigned)ih < (unsigned)H) && ((unsigned)iw < (unsigned)W)) ? xb[ih*W + iw] : 0.f;
        int k = k0 + r;
        a0 = fmaf(ctw[k],          xv, a0);
        a1 = fmaf(pdw[k],          xv, a1);
        a2 = fmaf(pdw[KTOT + k],   xv, a2);
        a3 = fmaf(pdw[2*KTOT + k], xv, a3);
        a4 = fmaf(pdw[3*KTOT + k], xv, a4);
      }
    }
  }
  __shared__ float red[4][64][5];
  red[q][p][0] = a0; red[q][p][1] = a1; red[q][p][2] = a2; red[q][p][3] = a3; red[q][p][4] = a4;
  __syncthreads();
  if (q == 0 && ok) {
    float s0 = red[0][p][0] + red[1][p][0] + red[2][p][0] + red[3][p][0];
    float s1 = red[0][p][1] + red[1][p][1] + red[2][p][1] + red[3][p][1];
    float s2 = red[0][p][2] + red[1][p][2] + red[2][p][2] + red[3][p][2];
    float s3 = red[0][p][3] + red[1][p][3] + red[2][p][3] + red[3][p][3];
    float s4 = red[0][p][4] + red[1][p][4] + red[2][p][4] + red[3][p][4];
    const int gi = 2*LCUM[l] + bb*HW + hw;
    ctrp[gi] = 1.0f/(1.0f + expf(-(s0 + ctb[0])));
    const float sc = scl[l];
    float* rg = regb + (size_t)gi*4;
    rg[0] = fmaxf((s1 + pdb[0])*sc, 0.f);
    rg[1] = fmaxf((s2 + pdb[1])*sc, 0.f);
    rg[2] = fmaxf((s3 + pdb[2])*sc, 0.f);
    rg[3] = fmaxf((s4 + pdb[3])*sc, 0.f);
  }
}

// ---------------- top-k pipeline ----------------
__global__ void k_init(uint32_t* __restrict__ hist, uint32_t* __restrict__ ctrA,
                       uint32_t* __restrict__ ctrB) {
  int i = blockIdx.x*blockDim.x + threadIdx.x;
  if (i < 40960) hist[i] = 0;
  if (i < 10) { ctrA[i] = 0; ctrB[i] = 0; }
}

__global__ __launch_bounds__(256)
void k_hist(const float* __restrict__ scores, uint32_t* __restrict__ hist) {
  const int sid = blockIdx.y; const int l = sid >> 1, b = sid & 1;
  const int HW = LHW[l]; const int size = NCLS*HW;
  const float* sb = scores + (size_t)NCLS*(2*LCUM[l] + b*HW);
  __shared__ uint32_t h[4096];
  for (int i = threadIdx.x; i < 4096; i += 256) h[i] = 0;
  __syncthreads();
  const int base = blockIdx.x*4096;
  if (base < size) {
    for (int j = 0; j < 16; j++) {
      int i = base + threadIdx.x + j*256;
      if (i < size) {
        uint32_t bkt = __float_as_uint(sb[i]) >> 20;
        lds_hist_add(h, bkt);
      }
    }
  }
  __syncthreads();
  uint32_t* gh = hist + (size_t)sid*4096;
  for (int i = threadIdx.x; i < 4096; i += 256) { uint32_t v = h[i]; if (v) atomicAdd(&gh[i], v); }
}

__global__ __launch_bounds__(256)
void k_select(const uint32_t* __restrict__ hist, int* __restrict__ meta) {
  const int sid = blockIdx.x;
  const uint32_t* gh = hist + (size_t)sid*4096;
  __shared__ uint32_t ps[256];
  uint32_t sum = 0;
  for (int i = 0; i < 16; i++) sum += gh[threadIdx.x*16 + i];
  ps[threadIdx.x] = sum;
  __syncthreads();
  if (threadIdx.x == 0) {
    uint32_t c = 0; int T = 0, m = 1000;
    for (int ch = 255; ch >= 0; --ch) {
      if (c + ps[ch] >= 1000u) {
        for (int t = ch*16 + 15; t >= ch*16; --t) {
          uint32_t hv = gh[t];
          if (c + hv >= 1000u) { T = t; m = (int)(1000u - c); break; }
          c += hv;
        }
        break;
      }
      c += ps[ch];
    }
    meta[sid*4 + 0] = T;
    meta[sid*4 + 1] = (int)c;
    meta[sid*4 + 2] = m;
    meta[sid*4 + 3] = (int)gh[T];
  }
}

__global__ __launch_bounds__(256)
void k_collect(const float* __restrict__ scores, const int* __restrict__ meta,
               unsigned long long* __restrict__ listA, unsigned long long* __restrict__ listB,
               uint32_t* __restrict__ ctrA, uint32_t* __restrict__ ctrB) {
  const int sid = blockIdx.y; const int l = sid >> 1, b = sid & 1;
  const int HW = LHW[l]; const int size = NCLS*HW;
  const size_t sbase = (size_t)NCLS*(2*LCUM[l] + b*HW);
  const float* sb = scores + sbase;
  unsigned long long* lB = listB + sbase;
  unsigned long long* lA = listA + (size_t)sid*1024;
  const uint32_t T = (uint32_t)meta[sid*4];
  const int base = blockIdx.x*4096;
  if (base >= size) return;
  for (int j = 0; j < 16; j++) {
    int i = base + threadIdx.x + j*256;
    if (i >= size) continue;
    float sv = sb[i];
    uint32_t bits = __float_as_uint(sv);
    uint32_t bkt = bits >> 20;
    if (bkt < T) continue;
    int cls = i / HW; int hw = i - cls*HW;
    uint32_t idx = (uint32_t)(hw*NCLS + cls);
    unsigned long long key = ((unsigned long long)bits << 32) | (unsigned long long)(0xFFFFFFFFu - idx);
    if (bkt > T) {
      uint32_t pos = wave_append_pos(&ctrA[sid]);
      if (pos < 1024u) lA[pos] = key;
    } else {
      uint32_t pos = wave_append_pos(&ctrB[sid]);
      lB[pos] = key;
    }
  }
}

__global__ __launch_bounds__(1024)
void k_refine(const int* __restrict__ meta, const unsigned long long* __restrict__ listB,
              unsigned long long* __restrict__ listA, uint32_t* __restrict__ ctrA) {
  const int sid = blockIdx.x; const int l = sid >> 1, b = sid & 1;
  const int HW = LHW[l];
  const size_t sbase = (size_t)NCLS*(2*LCUM[l] + b*HW);
  const unsigned long long* lB = listB + sbase;
  const int nB = meta[sid*4 + 3];
  int m = meta[sid*4 + 2];
  __shared__ uint32_t h[256];
  __shared__ unsigned long long sPre;
  __shared__ int sM;
  unsigned long long prefix = 0, mask = 0;
  for (int p = 7; p >= 0; --p) {
    for (int i = threadIdx.x; i < 256; i += 1024) h[i] = 0;
    __syncthreads();
    for (int i = threadIdx.x; i < nB; i += 1024) {
      unsigned long long k = lB[i];
      if ((k & mask) == prefix) {
        uint32_t bkt = (uint32_t)((k >> (p*8)) & 255ull);
        lds_hist_add(h, bkt);
      }
    }
    __syncthreads();
    if (threadIdx.x == 0) {
      uint32_t c = 0; int sel = 0; int mnew = m;
      for (int t = 255; t >= 0; --t) {
        if (c + h[t] >= (uint32_t)m) { sel = t; mnew = m - (int)c; break; }
        c += h[t];
      }
      sPre = prefix | ((unsigned long long)sel << (p*8));
      sM = mnew;
    }
    __syncthreads();
    prefix = sPre; m = sM;
    mask |= (0xFFull << (p*8));
    __syncthreads();
  }
  for (int i = threadIdx.x; i < nB; i += 1024) {
    unsigned long long k = lB[i];
    if (k >= prefix) {
      uint32_t pos = wave_append_pos(&ctrA[sid]);
      if (pos < 1024u) listA[(size_t)sid*1024 + pos] = k;
    }
  }
}

__global__ __launch_bounds__(256)
void k_sortdec(const unsigned long long* __restrict__ listA, const uint32_t* __restrict__ ctrA,
               const float* __restrict__ regb, float* __restrict__ cbox,
               float* __restrict__ cscr, float* __restrict__ ccls) {
  const int sid = blockIdx.x; const int l = sid >> 1, b = sid & 1;
  const int HW = LHW[l], W = LW[l];
  __shared__ unsigned long long key[1024];
  int n = (int)ctrA[sid]; if (n > 1024) n = 1024;
  for (int i = threadIdx.x; i < 1024; i += 256)
    key[i] = (i < n) ? listA[(size_t)sid*1024 + i] : 0ull;
  __syncthreads();
  for (int len = 2; len <= 1024; len <<= 1) {
    for (int j = len >> 1; j > 0; j >>= 1) {
      for (int t = threadIdx.x; t < 512; t += 256) {
        int i = ((t & ~(j - 1)) << 1) | (t & (j - 1));
        int pp = i | j;
        unsigned long long a = key[i], bq = key[pp];
        bool desc = ((i & len) == 0);
        if ((a < bq) == desc) { key[i] = bq; key[pp] = a; }
      }
      __syncthreads();
    }
  }
  for (int r = threadIdx.x; r < 1000; r += 256) {
    unsigned long long k = key[r];
    uint32_t bits = (uint32_t)(k >> 32);
    uint32_t idx = 0xFFFFFFFFu - (uint32_t)(k & 0xFFFFFFFFull);
    float val = __uint_as_float(bits);
    float sc = sqrtf(fmaxf(val, 1e-12f));
    int cls = (int)(idx % NCLS); int loc = (int)(idx / NCLS);
    int hh = loc / W; int ww = loc - hh*W;
    float cx = (float)(ww*LSTR[l] + (LSTR[l] >> 1));
    float cy = (float)(hh*LSTR[l] + (LSTR[l] >> 1));
    const float* rg = regb + (size_t)(2*LCUM[l] + b*HW + loc)*4;
    int slot = b*5000 + l*1000 + r;
    cbox[slot*4 + 0] = cx - rg[0];
    cbox[slot*4 + 1] = cy - rg[1];
    cbox[slot*4 + 2] = cx + rg[2];
    cbox[slot*4 + 3] = cy + rg[3];
    cscr[slot] = sc;
    ccls[slot] = (float)cls;
  }
}

// ---------------- NMS ----------------
__global__ __launch_bounds__(1024)
void k_nms(const float* __restrict__ cbox, const float* __restrict__ cscr,
           const float* __restrict__ ccls, float* __restrict__ out) {
  const int b = blockIdx.x;
  const int tid = threadIdx.x;
  __shared__ float s[5000];
  __shared__ float wv[16]; __shared__ int wi[16];
  __shared__ float bbx[5]; __shared__ int sBi; __shared__ float sBv;
  float x1[5], y1[5], x2[5], y2[5], ar[5];
#pragma unroll
  for (int r = 0; r < 5; r++) {
    int j = tid + r*1024;
    if (j < 5000) {
      const float4 bx = *reinterpret_cast<const float4*>(cbox + ((size_t)b*5000 + j)*4);
      float off = ccls[b*5000 + j]*10000.0f;
      x1[r] = bx.x + off; y1[r] = bx.y + off; x2[r] = bx.z + off; y2[r] = bx.w + off;
      ar[r] = (x2[r] - x1[r])*(y2[r] - y1[r]);
      s[j] = cscr[b*5000 + j];
    }
  }
  __syncthreads();
  for (int it = 0; it < 100; ++it) {
    float best = -1e30f; int bi = 0x7FFFFFFF;
#pragma unroll
    for (int r = 0; r < 5; r++) {
      int j = tid + r*1024;
      if (j < 5000) {
        float v = s[j];
        if (v > best || (v == best && j < bi)) { best = v; bi = j; }
      }
    }
    for (int o = 32; o > 0; o >>= 1) {
      float ov = __shfl_down(best, o, 64); int oi = __shfl_down(bi, o, 64);
      if (ov > best || (ov == best && oi < bi)) { best = ov; bi = oi; }
    }
    if ((tid & 63) == 0) { wv[tid >> 6] = best; wi[tid >> 6] = bi; }
    __syncthreads();
    if (tid < 64) {
      float v = (tid < 16) ? wv[tid] : -1e30f; int ix = (tid < 16) ? wi[tid] : 0x7FFFFFFF;
      for (int o = 8; o > 0; o >>= 1) {
        float ov = __shfl_down(v, o, 64); int oi = __shfl_down(ix, o, 64);
        if (ov > v || (ov == v && oi < ix)) { v = ov; ix = oi; }
      }
      if (tid == 0) { sBi = ix; sBv = v; }
    }
    __syncthreads();
    const int pick = sBi; const float pv = sBv;
    if (tid == (pick & 1023)) {
      const int r = pick >> 10;
      bbx[0] = x1[r]; bbx[1] = y1[r]; bbx[2] = x2[r]; bbx[3] = y2[r]; bbx[4] = ar[r];
      float* orow = out + ((size_t)b*100 + it)*6;
      if (pv > 0.f) {
        const float4 obx = *reinterpret_cast<const float4*>(cbox + ((size_t)b*5000 + pick)*4);
        orow[0] = obx.x; orow[1] = obx.y; orow[2] = obx.z; orow[3] = obx.w;
        orow[4] = pv; orow[5] = ccls[b*5000 + pick];
      } else {
        orow[0] = 0.f; orow[1] = 0.f; orow[2] = 0.f; orow[3] = 0.f; orow[4] = 0.f; orow[5] = 0.f;
      }
    }
    __syncthreads();
    const float bx1 = bbx[0], by1 = bbx[1], bx2 = bbx[2], by2 = bbx[3], ba = bbx[4];
#pragma unroll
    for (int r = 0; r < 5; r++) {
      int j = tid + r*1024;
      if (j < 5000) {
        float ix1 = fmaxf(bx1, x1[r]), iy1 = fmaxf(by1, y1[r]);
        float ix2 = fminf(bx2, x2[r]), iy2 = fminf(by2, y2[r]);
        float iw = fmaxf(ix2 - ix1, 0.f), ih = fmaxf(iy2 - iy1, 0.f);
        float inter = iw*ih;
        float iou = inter/((ba + ar[r] - inter) + 1e-9f);
        if (iou > 0.6f || j == pick) s[j] = -1.0f;
      }
    }
    __syncthreads();
  }
}

// ---------------- host launch ----------------
static inline size_t alignup(size_t x) { return (x + 255) & ~(size_t)255; }

extern "C" void kernel_launch(void* const* d_in, const int* in_sizes, int n_in,
                              void* d_out, int out_size, void* d_ws, size_t ws_size,
                              hipStream_t stream) {
  const float* p[5] = {(const float*)d_in[0], (const float*)d_in[1], (const float*)d_in[2],
                       (const float*)d_in[3], (const float*)d_in[4]};
  const float* cls_w   = (const float*)d_in[5];
  const float* cls_b   = (const float*)d_in[6];
  const float* box_w   = (const float*)d_in[7];
  const float* box_b   = (const float*)d_in[8];
  const float* logit_w = (const float*)d_in[9];
  const float* logit_b = (const float*)d_in[10];
  const float* pred_w  = (const float*)d_in[11];
  const float* pred_b  = (const float*)d_in[12];
  const float* ctr_w   = (const float*)d_in[13];
  const float* ctr_b   = (const float*)d_in[14];
  const float* scales  = (const float*)d_in[15];

  const size_t ACTF = (size_t)2*CINCH*TOTHW;           // floats per tower act
  const size_t ACT_BYTES = ACTF*4;                     // 41,506,816
  const size_t MISC_BYTES =
      alignup((size_t)4*2*TOTHW*4) + alignup((size_t)2*TOTHW*4) + alignup((size_t)40960*4) +
      alignup((size_t)40*4) + 256 + 256 + alignup((size_t)10*1024*8) +
      alignup((size_t)2*5000*4*4) + alignup((size_t)2*5000*4) + alignup((size_t)2*5000*4);
  const bool merged = ws_size >= (4*ACT_BYTES + MISC_BYTES);

  char* base = (char*)d_ws;
  float* Ta = (float*)base;                                  // merged: [tower][act]
  float* Tb = (float*)(base + (merged ? 2*ACT_BYTES : ACT_BYTES));
  char* sm = base + (merged ? 4*ACT_BYTES : 2*ACT_BYTES);
  float* regb = (float*)sm;            sm += alignup((size_t)4*2*TOTHW*4);
  float* ctrp = (float*)sm;            sm += alignup((size_t)2*TOTHW*4);
  uint32_t* hist = (uint32_t*)sm;      sm += alignup((size_t)40960*4);
  int* meta = (int*)sm;                sm += alignup((size_t)40*4);
  uint32_t* ctrA = (uint32_t*)sm;      sm += 256;
  uint32_t* ctrB = (uint32_t*)sm;      sm += 256;
  unsigned long long* listA = (unsigned long long*)sm; sm += alignup((size_t)10*1024*8);
  float* cbox = (float*)sm;            sm += alignup((size_t)2*5000*4*4);
  float* cscr = (float*)sm;            sm += alignup((size_t)2*5000*4);
  float* ccls = (float*)sm;            sm += alignup((size_t)2*5000*4);
  float* scores = Ta;                                  // Ta free when logits runs
  unsigned long long* listB = (unsigned long long*)Tb; // Tb free after heads consume it

  const size_t WSTRIDE = (size_t)CINCH*KTOT;           // per-layer weight stride

  hipLaunchKernelGGL(k_init, dim3(160), dim3(256), 0, stream, hist, ctrA, ctrB);

  auto setTower = [&](ConvArgs& a, int t, const float* wbase, const float* bbase, int layer,
                      const float* inb, float* outb) {
    a.w[t] = wbase + (size_t)layer*WSTRIDE;
    a.b[t] = bbase + layer*CINCH;
    a.out[t] = outb;
    for (int l = 0; l < 5; l++)
      a.in[t*5 + l] = inb ? (inb + (size_t)(2*CINCH)*LCUM[l]) : p[l];
  };

  if (merged) {
    // both towers in one dispatch per layer: grid (638, 2) = 1276 workgroups
    for (int layer = 0; layer < 4; layer++) {
      ConvArgs a; a.nt = 2; a.ctrp = nullptr;
      const float* inb0 = (layer == 0) ? nullptr : ((layer & 1) ? Ta : Tb);
      float* outb0 = (layer & 1) ? Tb : Ta;            // L0->Ta, L1->Tb, L2->Ta, L3->Tb
      // note: L0 in = p (nullptr marker), L1 in = Ta, L2 in = Tb, L3 in = Ta
      const float* inB = (layer == 0) ? nullptr : (((layer - 1) & 1) ? Tb : Ta);
      setTower(a, 0, box_w, box_b, layer, inB, outb0);
      setTower(a, 1, cls_w, cls_b, layer, inB ? (inB + ACTF) : nullptr, outb0 + ACTF);
      hipLaunchKernelGGL(conv_k<0>, dim3(2*NPXB128, 2), dim3(256), 0, stream, a);
    }
    // heads: box tower final act = Tb, cls tower final act = Tb + ACTF
    hipLaunchKernelGGL(k_head, dim3(NPXB64), dim3(256), 0, stream, Tb, ctr_w, ctr_b,
                       pred_w, pred_b, scales, ctrp, regb);
    ConvArgs a1; a1.nt = 1; a1.ctrp = ctrp;
    a1.w[0] = logit_w; a1.b[0] = logit_b; a1.out[0] = scores;
    a1.w[1] = logit_w; a1.b[1] = logit_b; a1.out[1] = scores;
    for (int l = 0; l < 5; l++) {
      a1.in[l] = Tb + ACTF + (size_t)(2*CINCH)*LCUM[l];
      a1.in[5 + l] = a1.in[l];
    }
    hipLaunchKernelGGL(conv_k<1>, dim3(NPXB128, 1), dim3(256), 0, stream, a1);
  } else {
    // sequential fallback (fits in 2 act buffers)
    auto run_tower = [&](const float* wbase, const float* bbase) {
      for (int layer = 0; layer < 4; layer++) {
        ConvArgs a; a.nt = 1; a.ctrp = nullptr;
        const float* inB = (layer == 0) ? nullptr : (((layer - 1) & 1) ? Tb : Ta);
        float* outb = (layer & 1) ? Tb : Ta;
        setTower(a, 0, wbase, bbase, layer, inB, outb);
        setTower(a, 1, wbase, bbase, layer, inB, outb);
        hipLaunchKernelGGL(conv_k<0>, dim3(NPXB128, 2), dim3(256), 0, stream, a);
      }
    };
    run_tower(box_w, box_b);   // final act in Tb
    hipLaunchKernelGGL(k_head, dim3(NPXB64), dim3(256), 0, stream, Tb, ctr_w, ctr_b,
                       pred_w, pred_b, scales, ctrp, regb);
    run_tower(cls_w, cls_b);   // final act in Tb
    ConvArgs a1; a1.nt = 1; a1.ctrp = ctrp;
    a1.w[0] = logit_w; a1.b[0] = logit_b; a1.out[0] = scores;
    a1.w[1] = logit_w; a1.b[1] = logit_b; a1.out[1] = scores;
    for (int l = 0; l < 5; l++) {
      a1.in[l] = Tb + (size_t)(2*CINCH)*LCUM[l];
      a1.in[5 + l] = a1.in[l];
    }
    hipLaunchKernelGGL(conv_k<1>, dim3(NPXB128, 1), dim3(256), 0, stream, a1);
  }

  // ---- top-k + decode + NMS ----
  hipLaunchKernelGGL(k_hist,    dim3(297, 10), dim3(256), 0, stream, scores, hist);
  hipLaunchKernelGGL(k_select,  dim3(10), dim3(256), 0, stream, hist, meta);
  hipLaunchKernelGGL(k_collect, dim3(297, 10), dim3(256), 0, stream, scores, meta, listA, listB, ctrA, ctrB);
  hipLaunchKernelGGL(k_refine,  dim3(10), dim3(1024), 0, stream, meta, listB, listA, ctrA);
  hipLaunchKernelGGL(k_sortdec, dim3(10), dim3(256), 0, stream, listA, ctrA, regb, cbox, cscr, ccls);
  hipLaunchKernelGGL(k_nms,     dim3(2), dim3(1024), 0, stream, cbox, cscr, ccls, (float*)d_out);
}

// Round 4
// 3628.783 us; speedup vs baseline: 2.3695x; 2.3695x over previous
//
#include <hip/hip_runtime.h>
#include <stdint.h>
#include <math.h>

#define NCLS 80
#define TOTHW 20267

typedef __bf16 bf16x8 __attribute__((ext_vector_type(8)));
typedef float f32x4 __attribute__((ext_vector_type(4)));
typedef short s16x8 __attribute__((ext_vector_type(8)));

static constexpr int cLW[5]    = {152,76,38,19,10};
static constexpr int cLH[5]    = {100,50,25,13,7};
static constexpr int cLHW[5]   = {15200,3800,950,247,70};
static constexpr int cLCUM[5]  = {0,15200,19000,19950,20197};
static constexpr int cLSTR[5]  = {8,16,32,64,128};
// conv px-blocks (128 px of padded plane) per (l,b) plane, cumulative
static constexpr int cCB[11]   = {0,123,246,278,310,319,328,331,334,335,336};
// padded-plane px base (capacity = blocks*128), cumulative
static constexpr int cPBASE[11]= {0,15744,31488,35584,39680,40832,41984,42368,42752,42880,43008};
// interior rows per (l,b) plane, cumulative (for k_prep)
static constexpr int cRCUM[11] = {0,100,200,250,300,325,350,363,376,383,390};
static constexpr int cCPX64[6] = {0,475,594,624,632,635};
#define NPXB64 635
#define SBE 11010048ull   // 43008*256 elements per split buffer

// ---------------- helpers ----------------
__device__ __forceinline__ void split3(float y, unsigned short& h0, unsigned short& h1, unsigned short& h2) {
  __bf16 b0 = (__bf16)y; float f0 = (float)b0;
  float r1 = y - f0;
  __bf16 b1 = (__bf16)r1; float f1 = (float)b1;
  __bf16 b2 = (__bf16)(r1 - f1);
  h0 = __builtin_bit_cast(unsigned short, b0);
  h1 = __builtin_bit_cast(unsigned short, b1);
  h2 = __builtin_bit_cast(unsigned short, b2);
}

__device__ __forceinline__ void lds_hist_add(uint32_t* h, uint32_t bucket) {
  unsigned long long act = __ballot(1);
  int lane = (int)(threadIdx.x & 63u);
  int leader = __ffsll(act) - 1;
  uint32_t lb = (uint32_t)__shfl((int)bucket, leader, 64);
  unsigned long long same = __ballot(bucket == lb);
  if (same == act) {
    if (lane == leader) atomicAdd(&h[bucket], (uint32_t)__popcll(act));
  } else {
    atomicAdd(&h[bucket], 1u);
  }
}

__device__ __forceinline__ uint32_t wave_append_pos(uint32_t* ctr) {
  unsigned long long act = __ballot(1);
  int lane = (int)(threadIdx.x & 63u);
  int leader = __ffsll(act) - 1;
  uint32_t cnt  = (uint32_t)__popcll(act);
  uint32_t rank = (uint32_t)__popcll(act & ((1ull << lane) - 1ull));
  uint32_t base = 0;
  if (lane == leader) base = atomicAdd(ctr, cnt);
  base = (uint32_t)__shfl((int)base, leader, 64);
  return base + rank;
}

// ---------------- zero borders/gaps of a split-triple region ----------------
__global__ void k_zero(unsigned short* X0, unsigned short* X1, unsigned short* X2) {
  int px = blockIdx.x * 256 + threadIdx.x;
  if (px >= 43008) return;
  int pi = 0;
#pragma unroll
  for (int i = 1; i < 10; i++) if (px >= cPBASE[i]) pi = i;
  const int l = pi >> 1;
  const int p = px - cPBASE[pi];
  const int W = cLW[l], H = cLH[l], PWl = W + 2;
  const int pr = p / PWl, pc = p - pr * PWl;
  if (pr >= 1 && pr <= H && pc >= 1 && pc <= W) return;  // interior: left alone
  s16x8 z = {0,0,0,0,0,0,0,0};
  size_t base = (size_t)px * 256;
#pragma unroll
  for (int k = 0; k < 32; k++) {
    *reinterpret_cast<s16x8*>(X0 + base + k*8) = z;
    *reinterpret_cast<s16x8*>(X1 + base + k*8) = z;
    *reinterpret_cast<s16x8*>(X2 + base + k*8) = z;
  }
}

// ---------------- stage inputs -> padded px-major bf16 splits ----------------
__global__ __launch_bounds__(256)
void k_prep(const float* __restrict__ p0, const float* __restrict__ p1,
            const float* __restrict__ p2, const float* __restrict__ p3,
            const float* __restrict__ p4,
            unsigned short* __restrict__ X0, unsigned short* __restrict__ X1,
            unsigned short* __restrict__ X2) {
  int bx = blockIdx.x;
  int pi = 0;
#pragma unroll
  for (int i = 1; i < 10; i++) if (bx >= cRCUM[i]) pi = i;
  const int h = bx - cRCUM[pi];
  const int l = pi >> 1, bidx = pi & 1;
  const int W = cLW[l], HW = cLHW[l], PWl = W + 2;
  const int PB = cPBASE[pi];
  const float* src;
  if (l == 0) src = p0; else if (l == 1) src = p1; else if (l == 2) src = p2;
  else if (l == 3) src = p3; else src = p4;
  src += (size_t)bidx * 256 * HW;
  const int tid = threadIdx.x;
  __shared__ float tile[64][152];
  for (int c0 = 0; c0 < 256; c0 += 64) {
    {
      int c = tid >> 2, wq = tid & 3;
      for (int w = wq; w < W; w += 4)
        tile[c][w] = src[(size_t)(c0 + c) * HW + h * W + w];
    }
    __syncthreads();
    {
      int c8 = (tid & 7) * 8;
      for (int w = tid >> 3; w < W; w += 32) {
        size_t base = (size_t)(PB + (h + 1) * PWl + (w + 1)) * 256 + c0 + c8;
        unsigned short a0[8], a1[8], a2[8];
#pragma unroll
        for (int j = 0; j < 8; j++) split3(tile[c8 + j][w], a0[j], a1[j], a2[j]);
        *reinterpret_cast<s16x8*>(X0 + base) = *reinterpret_cast<s16x8*>(a0);
        *reinterpret_cast<s16x8*>(X1 + base) = *reinterpret_cast<s16x8*>(a1);
        *reinterpret_cast<s16x8*>(X2 + base) = *reinterpret_cast<s16x8*>(a2);
      }
    }
    __syncthreads();
  }
}

// ---------------- pack weights [Cout][256][3][3] -> [r][s][256][256] bf16 ----------------
__global__ void k_pack(const float* __restrict__ w, unsigned short* __restrict__ wp) {
  const int oc = blockIdx.x, c = threadIdx.x;
#pragma unroll
  for (int r = 0; r < 9; r++) {
    float v = w[((size_t)oc * 256 + c) * 9 + r];
    unsigned short h0, h1, h2;
    split3(v, h0, h1, h2);
    wp[((size_t)(r * 3 + 0) * 256 + oc) * 256 + c] = h0;
    wp[((size_t)(r * 3 + 1) * 256 + oc) * 256 + c] = h1;
    wp[((size_t)(r * 3 + 2) * 256 + oc) * 256 + c] = h2;
  }
}

// ---------------- MFMA conv: C[p][oc] = sum_r sum_c X[p+off_r][c] W_r[c][oc] ----------------
// EPI 0: relu+bias -> write bf16 splits (px-major)
// EPI 1: relu+bias -> write fp32 act in [l][b][c][hw] layout (for k_head)
// EPI 2: logits: bias -> sigmoid * ctrp -> threshold -> scores [l][b][cls][hw]
struct MfArgs {
  const unsigned short *X0, *X1, *X2;
  const unsigned short *Wp;
  const float* bias;
  unsigned short *Y0, *Y1, *Y2;
  float* actf;
  float* scores;
  const float* ctrp;
};

template<int EPI>
__global__ __launch_bounds__(256, 2)
void conv_mfma(MfArgs a) {
  __shared__ __align__(16) unsigned short lds[24576];  // A rows 0..127, B rows 128..255, KP=96
  const int tid = threadIdx.x;
  const int lane = tid & 63;
  const int wid = tid >> 6;

  int bx = blockIdx.x;
  int pi = 0;
#pragma unroll
  for (int i = 1; i < 10; i++) if (bx >= cCB[i]) pi = i;
  const int l = pi >> 1, bidx = pi & 1;
  const int pxb = bx - cCB[pi];
  const int px0 = pxb * 128;
  const int PB = cPBASE[pi];
  const int W = cLW[l], H = cLH[l], HW = cLHW[l], PWl = W + 2;
  const int oc0 = blockIdx.y * 128;

  // staging mapping: slot d in {0,1}: idx2 = tid + d*256 -> row (0..127), g (0..3)
  int row_[2], g_[2];
  int wA[3][2];
#pragma unroll
  for (int d = 0; d < 2; d++) {
    int idx2 = tid + d * 256;
    row_[d] = idx2 >> 2;
    g_[d] = idx2 & 3;
    int rm = (5 * row_[d]) % 12;
#pragma unroll
    for (int s = 0; s < 3; s++) {
      int ch = s * 4 + g_[d] + rm; if (ch >= 12) ch -= 12; if (ch >= 12) ch -= 12;
      wA[s][d] = row_[d] * 96 + ch * 8;
    }
  }

  // fragment read offsets (constant across k-steps)
  const int wr = wid >> 1, wc = wid & 1;
  const int kg = lane >> 4, ln15 = lane & 15;
  int fA[4][3], fB[4][3];
#pragma unroll
  for (int mt = 0; mt < 4; mt++) {
    int rowA = wr * 64 + mt * 16 + ln15;
    int rm = (5 * rowA) % 12;
#pragma unroll
    for (int s = 0; s < 3; s++) {
      int ch = s * 4 + kg + rm; if (ch >= 12) ch -= 12; if (ch >= 12) ch -= 12;
      fA[mt][s] = rowA * 96 + ch * 8;
    }
  }
#pragma unroll
  for (int nt = 0; nt < 4; nt++) {
    int rowB = wc * 64 + nt * 16 + ln15;
    int rm = (5 * rowB) % 12;
#pragma unroll
    for (int s = 0; s < 3; s++) {
      int ch = s * 4 + kg + rm; if (ch >= 12) ch -= 12; if (ch >= 12) ch -= 12;
      fB[nt][s] = (128 + rowB) * 96 + ch * 8;
    }
  }

  f32x4 acc[4][4];
#pragma unroll
  for (int mt = 0; mt < 4; mt++)
#pragma unroll
    for (int nt = 0; nt < 4; nt++) acc[mt][nt] = (f32x4){0.f, 0.f, 0.f, 0.f};

  for (int step = 0; step < 72; ++step) {
    const int rr = step >> 3;
    const int c0 = (step & 7) << 5;
    const int dh = rr / 3 - 1, dw = rr - (rr / 3) * 3 - 1;
    const long long OFF = (long long)(PB + px0 + dh * PWl + dw);
    s16x8 ra[6], rb[6];
#pragma unroll
    for (int s = 0; s < 3; s++) {
      const unsigned short* Xs = (s == 0) ? a.X0 : (s == 1) ? a.X1 : a.X2;
      const unsigned short* Ws = a.Wp + (size_t)(rr * 3 + s) * 65536;
#pragma unroll
      for (int d = 0; d < 2; d++) {
        ra[s * 2 + d] = *reinterpret_cast<const s16x8*>(Xs + (OFF + row_[d]) * 256 + c0 + g_[d] * 8);
        rb[s * 2 + d] = *reinterpret_cast<const s16x8*>(Ws + (size_t)(oc0 + row_[d]) * 256 + c0 + g_[d] * 8);
      }
    }
    if (step) __syncthreads();   // previous frag reads done before overwrite
#pragma unroll
    for (int s = 0; s < 3; s++)
#pragma unroll
      for (int d = 0; d < 2; d++) {
        *reinterpret_cast<s16x8*>(&lds[wA[s][d]]) = ra[s * 2 + d];
        *reinterpret_cast<s16x8*>(&lds[wA[s][d] + 12288]) = rb[s * 2 + d];
      }
    __syncthreads();

    bf16x8 bv[4][3];
#pragma unroll
    for (int nt = 0; nt < 4; nt++)
#pragma unroll
      for (int s = 0; s < 3; s++)
        bv[nt][s] = *reinterpret_cast<const bf16x8*>(&lds[fB[nt][s]]);
#pragma unroll
    for (int mt = 0; mt < 4; mt++) {
      bf16x8 av0 = *reinterpret_cast<const bf16x8*>(&lds[fA[mt][0]]);
      bf16x8 av1 = *reinterpret_cast<const bf16x8*>(&lds[fA[mt][1]]);
      bf16x8 av2 = *reinterpret_cast<const bf16x8*>(&lds[fA[mt][2]]);
#pragma unroll
      for (int nt = 0; nt < 4; nt++) {
        acc[mt][nt] = __builtin_amdgcn_mfma_f32_16x16x32_bf16(av0, bv[nt][0], acc[mt][nt], 0, 0, 0);
        acc[mt][nt] = __builtin_amdgcn_mfma_f32_16x16x32_bf16(av0, bv[nt][1], acc[mt][nt], 0, 0, 0);
        acc[mt][nt] = __builtin_amdgcn_mfma_f32_16x16x32_bf16(av1, bv[nt][0], acc[mt][nt], 0, 0, 0);
        acc[mt][nt] = __builtin_amdgcn_mfma_f32_16x16x32_bf16(av1, bv[nt][1], acc[mt][nt], 0, 0, 0);
        acc[mt][nt] = __builtin_amdgcn_mfma_f32_16x16x32_bf16(av0, bv[nt][2], acc[mt][nt], 0, 0, 0);
        acc[mt][nt] = __builtin_amdgcn_mfma_f32_16x16x32_bf16(av2, bv[nt][0], acc[mt][nt], 0, 0, 0);
      }
    }
  }
  __syncthreads();

  // epilogue
#pragma unroll
  for (int mt = 0; mt < 4; mt++) {
#pragma unroll
    for (int i = 0; i < 4; i++) {
      const int pxl = wr * 64 + mt * 16 + (lane >> 4) * 4 + i;
      const int p = px0 + pxl;
      const int pr = p / PWl, pc = p - pr * PWl;
      if (!(pr >= 1 && pr <= H && pc >= 1 && pc <= W)) continue;
      const int hw = (pr - 1) * W + (pc - 1);
#pragma unroll
      for (int nt = 0; nt < 4; nt++) {
        const int oc = oc0 + wc * 64 + nt * 16 + ln15;
        if (EPI == 2) {
          if (oc < NCLS) {
            float y = acc[mt][nt][i] + a.bias[oc];
            float pcs = 1.0f / (1.0f + expf(-y));
            float s = pcs * a.ctrp[2 * cLCUM[l] + bidx * HW + hw];
            s = (s > 0.05f) ? s : 0.f;
            a.scores[(size_t)NCLS * (2 * cLCUM[l] + bidx * HW) + (size_t)oc * HW + hw] = s;
          }
        } else {
          float y = fmaxf(acc[mt][nt][i] + a.bias[oc], 0.f);
          if (EPI == 0) {
            size_t o = (size_t)(PB + p) * 256 + oc;
            unsigned short h0, h1, h2;
            split3(y, h0, h1, h2);
            a.Y0[o] = h0; a.Y1[o] = h1; a.Y2[o] = h2;
          } else {
            a.actf[(size_t)512 * cLCUM[l] + (size_t)bidx * 256 * HW + (size_t)oc * HW + hw] = y;
          }
        }
      }
    }
  }
}

// ---------------- ctr + reg head (256 -> 5), reads fp32 act ----------------
__global__ __launch_bounds__(256)
void k_head(const float* __restrict__ act, const float* __restrict__ ctw,
            const float* __restrict__ ctb, const float* __restrict__ pdw,
            const float* __restrict__ pdb, const float* __restrict__ scl,
            float* __restrict__ ctrp, float* __restrict__ regb) {
  int bx = blockIdx.x; int l = 0;
#pragma unroll
  for (int i = 1; i < 5; i++) if (bx >= cCPX64[i]) l = i;
  const int lblk = bx - cCPX64[l];
  const int H = cLH[l], W = cLW[l], HW = cLHW[l]; const int N = 2 * HW;
  const int p = threadIdx.x & 63;
  const int q = threadIdx.x >> 6;
  const int px = lblk * 64 + p;
  float a0 = 0.f, a1 = 0.f, a2 = 0.f, a3 = 0.f, a4 = 0.f;
  int bb = 0, hw = 0, hh = 0, ww = 0;
  const bool ok = (px < N);
  if (ok) {
    bb = px / HW; hw = px - bb * HW; hh = hw / W; ww = hw - hh * W;
    const float* ab = act + (size_t)512 * cLCUM[l] + (size_t)bb * 256 * HW;
    for (int c = q * 64; c < q * 64 + 64; ++c) {
      const float* xb = ab + (size_t)c * HW;
      const int k0 = c * 9;
#pragma unroll
      for (int r = 0; r < 9; r++) {
        int dh = r / 3 - 1, dw = r % 3 - 1;
        int ih = hh + dh, iw = ww + dw;
        float xv = (((unsigned)ih < (unsigned)H) && ((unsigned)iw < (unsigned)W)) ? xb[ih * W + iw] : 0.f;
        int k = k0 + r;
        a0 = fmaf(ctw[k],           xv, a0);
        a1 = fmaf(pdw[k],           xv, a1);
        a2 = fmaf(pdw[2304 + k],    xv, a2);
        a3 = fmaf(pdw[2*2304 + k],  xv, a3);
        a4 = fmaf(pdw[3*2304 + k],  xv, a4);
      }
    }
  }
  __shared__ float red[4][64][5];
  red[q][p][0] = a0; red[q][p][1] = a1; red[q][p][2] = a2; red[q][p][3] = a3; red[q][p][4] = a4;
  __syncthreads();
  if (q == 0 && ok) {
    float s0 = red[0][p][0] + red[1][p][0] + red[2][p][0] + red[3][p][0];
    float s1 = red[0][p][1] + red[1][p][1] + red[2][p][1] + red[3][p][1];
    float s2 = red[0][p][2] + red[1][p][2] + red[2][p][2] + red[3][p][2];
    float s3 = red[0][p][3] + red[1][p][3] + red[2][p][3] + red[3][p][3];
    float s4 = red[0][p][4] + red[1][p][4] + red[2][p][4] + red[3][p][4];
    const int gi = 2 * cLCUM[l] + bb * HW + hw;
    ctrp[gi] = 1.0f / (1.0f + expf(-(s0 + ctb[0])));
    const float sc = scl[l];
    float* rg = regb + (size_t)gi * 4;
    rg[0] = fmaxf((s1 + pdb[0]) * sc, 0.f);
    rg[1] = fmaxf((s2 + pdb[1]) * sc, 0.f);
    rg[2] = fmaxf((s3 + pdb[2]) * sc, 0.f);
    rg[3] = fmaxf((s4 + pdb[3]) * sc, 0.f);
  }
}

// ---------------- top-k pipeline ----------------
__global__ void k_init(uint32_t* __restrict__ hist, uint32_t* __restrict__ ctrA,
                       uint32_t* __restrict__ ctrB) {
  int i = blockIdx.x * blockDim.x + threadIdx.x;
  if (i < 40960) hist[i] = 0;
  if (i < 10) { ctrA[i] = 0; ctrB[i] = 0; }
}

__global__ __launch_bounds__(256)
void k_hist(const float* __restrict__ scores, uint32_t* __restrict__ hist) {
  const int sid = blockIdx.y; const int l = sid >> 1, b = sid & 1;
  const int HW = cLHW[l]; const int size = NCLS * HW;
  const float* sb = scores + (size_t)NCLS * (2 * cLCUM[l] + b * HW);
  __shared__ uint32_t h[4096];
  for (int i = threadIdx.x; i < 4096; i += 256) h[i] = 0;
  __syncthreads();
  const int base = blockIdx.x * 4096;
  if (base < size) {
    for (int j = 0; j < 16; j++) {
      int i = base + threadIdx.x + j * 256;
      if (i < size) {
        uint32_t bkt = __float_as_uint(sb[i]) >> 20;
        lds_hist_add(h, bkt);
      }
    }
  }
  __syncthreads();
  uint32_t* gh = hist + (size_t)sid * 4096;
  for (int i = threadIdx.x; i < 4096; i += 256) { uint32_t v = h[i]; if (v) atomicAdd(&gh[i], v); }
}

__global__ __launch_bounds__(256)
void k_select(const uint32_t* __restrict__ hist, int* __restrict__ meta) {
  const int sid = blockIdx.x;
  const uint32_t* gh = hist + (size_t)sid * 4096;
  __shared__ uint32_t ps[256];
  uint32_t sum = 0;
  for (int i = 0; i < 16; i++) sum += gh[threadIdx.x * 16 + i];
  ps[threadIdx.x] = sum;
  __syncthreads();
  if (threadIdx.x == 0) {
    uint32_t c = 0; int T = 0, m = 1000;
    for (int ch = 255; ch >= 0; --ch) {
      if (c + ps[ch] >= 1000u) {
        for (int t = ch * 16 + 15; t >= ch * 16; --t) {
          uint32_t hv = gh[t];
          if (c + hv >= 1000u) { T = t; m = (int)(1000u - c); break; }
          c += hv;
        }
        break;
      }
      c += ps[ch];
    }
    meta[sid * 4 + 0] = T;
    meta[sid * 4 + 1] = (int)c;
    meta[sid * 4 + 2] = m;
    meta[sid * 4 + 3] = (int)gh[T];
  }
}

__global__ __launch_bounds__(256)
void k_collect(const float* __restrict__ scores, const int* __restrict__ meta,
               unsigned long long* __restrict__ listA, unsigned long long* __restrict__ listB,
               uint32_t* __restrict__ ctrA, uint32_t* __restrict__ ctrB) {
  const int sid = blockIdx.y; const int l = sid >> 1, b = sid & 1;
  const int HW = cLHW[l]; const int size = NCLS * HW;
  const size_t sbase = (size_t)NCLS * (2 * cLCUM[l] + b * HW);
  const float* sb = scores + sbase;
  unsigned long long* lB = listB + sbase;
  unsigned long long* lA = listA + (size_t)sid * 1024;
  const uint32_t T = (uint32_t)meta[sid * 4];
  const int base = blockIdx.x * 4096;
  if (base >= size) return;
  for (int j = 0; j < 16; j++) {
    int i = base + threadIdx.x + j * 256;
    if (i >= size) continue;
    float sv = sb[i];
    uint32_t bits = __float_as_uint(sv);
    uint32_t bkt = bits >> 20;
    if (bkt < T) continue;
    int cls = i / HW; int hw = i - cls * HW;
    uint32_t idx = (uint32_t)(hw * NCLS + cls);
    unsigned long long key = ((unsigned long long)bits << 32) | (unsigned long long)(0xFFFFFFFFu - idx);
    if (bkt > T) {
      uint32_t pos = wave_append_pos(&ctrA[sid]);
      if (pos < 1024u) lA[pos] = key;
    } else {
      uint32_t pos = wave_append_pos(&ctrB[sid]);
      lB[pos] = key;
    }
  }
}

__global__ __launch_bounds__(1024)
void k_refine(const int* __restrict__ meta, const unsigned long long* __restrict__ listB,
              unsigned long long* __restrict__ listA, uint32_t* __restrict__ ctrA) {
  const int sid = blockIdx.x; const int l = sid >> 1, b = sid & 1;
  const int HW = cLHW[l];
  const size_t sbase = (size_t)NCLS * (2 * cLCUM[l] + b * HW);
  const unsigned long long* lB = listB + sbase;
  const int nB = meta[sid * 4 + 3];
  int m = meta[sid * 4 + 2];
  __shared__ uint32_t h[256];
  __shared__ unsigned long long sPre;
  __shared__ int sM;
  unsigned long long prefix = 0, mask = 0;
  for (int p = 7; p >= 0; --p) {
    for (int i = threadIdx.x; i < 256; i += 1024) h[i] = 0;
    __syncthreads();
    for (int i = threadIdx.x; i < nB; i += 1024) {
      unsigned long long k = lB[i];
      if ((k & mask) == prefix) {
        uint32_t bkt = (uint32_t)((k >> (p * 8)) & 255ull);
        lds_hist_add(h, bkt);
      }
    }
    __syncthreads();
    if (threadIdx.x == 0) {
      uint32_t c = 0; int sel = 0; int mnew = m;
      for (int t = 255; t >= 0; --t) {
        if (c + h[t] >= (uint32_t)m) { sel = t; mnew = m - (int)c; break; }
        c += h[t];
      }
      sPre = prefix | ((unsigned long long)sel << (p * 8));
      sM = mnew;
    }
    __syncthreads();
    prefix = sPre; m = sM;
    mask |= (0xFFull << (p * 8));
    __syncthreads();
  }
  for (int i = threadIdx.x; i < nB; i += 1024) {
    unsigned long long k = lB[i];
    if (k >= prefix) {
      uint32_t pos = wave_append_pos(&ctrA[sid]);
      if (pos < 1024u) listA[(size_t)sid * 1024 + pos] = k;
    }
  }
}

__global__ __launch_bounds__(256)
void k_sortdec(const unsigned long long* __restrict__ listA, const uint32_t* __restrict__ ctrA,
               const float* __restrict__ regb, float* __restrict__ cbox,
               float* __restrict__ cscr, float* __restrict__ ccls) {
  const int sid = blockIdx.x; const int l = sid >> 1, b = sid & 1;
  const int HW = cLHW[l], W = cLW[l];
  __shared__ unsigned long long key[1024];
  int n = (int)ctrA[sid]; if (n > 1024) n = 1024;
  for (int i = threadIdx.x; i < 1024; i += 256)
    key[i] = (i < n) ? listA[(size_t)sid * 1024 + i] : 0ull;
  __syncthreads();
  for (int len = 2; len <= 1024; len <<= 1) {
    for (int j = len >> 1; j > 0; j >>= 1) {
      for (int t = threadIdx.x; t < 512; t += 256) {
        int i = ((t & ~(j - 1)) << 1) | (t & (j - 1));
        int pp = i | j;
        unsigned long long a = key[i], bq = key[pp];
        bool desc = ((i & len) == 0);
        if ((a < bq) == desc) { key[i] = bq; key[pp] = a; }
      }
      __syncthreads();
    }
  }
  for (int r = threadIdx.x; r < 1000; r += 256) {
    unsigned long long k = key[r];
    uint32_t bits = (uint32_t)(k >> 32);
    uint32_t idx = 0xFFFFFFFFu - (uint32_t)(k & 0xFFFFFFFFull);
    float val = __uint_as_float(bits);
    float sc = sqrtf(fmaxf(val, 1e-12f));
    int cls = (int)(idx % NCLS); int loc = (int)(idx / NCLS);
    int hh = loc / W; int ww = loc - hh * W;
    float cx = (float)(ww * cLSTR[l] + (cLSTR[l] >> 1));
    float cy = (float)(hh * cLSTR[l] + (cLSTR[l] >> 1));
    const float* rg = regb + (size_t)(2 * cLCUM[l] + b * HW + loc) * 4;
    int slot = b * 5000 + l * 1000 + r;
    cbox[slot * 4 + 0] = cx - rg[0];
    cbox[slot * 4 + 1] = cy - rg[1];
    cbox[slot * 4 + 2] = cx + rg[2];
    cbox[slot * 4 + 3] = cy + rg[3];
    cscr[slot] = sc;
    ccls[slot] = (float)cls;
  }
}

// ---------------- NMS ----------------
__global__ __launch_bounds__(1024)
void k_nms(const float* __restrict__ cbox, const float* __restrict__ cscr,
           const float* __restrict__ ccls, float* __restrict__ out) {
  const int b = blockIdx.x;
  const int tid = threadIdx.x;
  __shared__ float s[5000];
  __shared__ float wv[16]; __shared__ int wi[16];
  __shared__ float bbx[5]; __shared__ int sBi; __shared__ float sBv;
  float x1[5], y1[5], x2[5], y2[5], ar[5];
#pragma unroll
  for (int r = 0; r < 5; r++) {
    int j = tid + r * 1024;
    if (j < 5000) {
      const float4 bx = *reinterpret_cast<const float4*>(cbox + ((size_t)b * 5000 + j) * 4);
      float off = ccls[b * 5000 + j] * 10000.0f;
      x1[r] = bx.x + off; y1[r] = bx.y + off; x2[r] = bx.z + off; y2[r] = bx.w + off;
      ar[r] = (x2[r] - x1[r]) * (y2[r] - y1[r]);
      s[j] = cscr[b * 5000 + j];
    }
  }
  __syncthreads();
  for (int it = 0; it < 100; ++it) {
    float best = -1e30f; int bi = 0x7FFFFFFF;
#pragma unroll
    for (int r = 0; r < 5; r++) {
      int j = tid + r * 1024;
      if (j < 5000) {
        float v = s[j];
        if (v > best || (v == best && j < bi)) { best = v; bi = j; }
      }
    }
    for (int o = 32; o > 0; o >>= 1) {
      float ov = __shfl_down(best, o, 64); int oi = __shfl_down(bi, o, 64);
      if (ov > best || (ov == best && oi < bi)) { best = ov; bi = oi; }
    }
    if ((tid & 63) == 0) { wv[tid >> 6] = best; wi[tid >> 6] = bi; }
    __syncthreads();
    if (tid < 64) {
      float v = (tid < 16) ? wv[tid] : -1e30f; int ix = (tid < 16) ? wi[tid] : 0x7FFFFFFF;
      for (int o = 8; o > 0; o >>= 1) {
        float ov = __shfl_down(v, o, 64); int oi = __shfl_down(ix, o, 64);
        if (ov > v || (ov == v && oi < ix)) { v = ov; ix = oi; }
      }
      if (tid == 0) { sBi = ix; sBv = v; }
    }
    __syncthreads();
    const int pick = sBi; const float pv = sBv;
    if (tid == (pick & 1023)) {
      const int r = pick >> 10;
      bbx[0] = x1[r]; bbx[1] = y1[r]; bbx[2] = x2[r]; bbx[3] = y2[r]; bbx[4] = ar[r];
      float* orow = out + ((size_t)b * 100 + it) * 6;
      if (pv > 0.f) {
        const float4 obx = *reinterpret_cast<const float4*>(cbox + ((size_t)b * 5000 + pick) * 4);
        orow[0] = obx.x; orow[1] = obx.y; orow[2] = obx.z; orow[3] = obx.w;
        orow[4] = pv; orow[5] = ccls[b * 5000 + pick];
      } else {
        orow[0] = 0.f; orow[1] = 0.f; orow[2] = 0.f; orow[3] = 0.f; orow[4] = 0.f; orow[5] = 0.f;
      }
    }
    __syncthreads();
    const float bx1 = bbx[0], by1 = bbx[1], bx2 = bbx[2], by2 = bbx[3], ba = bbx[4];
#pragma unroll
    for (int r = 0; r < 5; r++) {
      int j = tid + r * 1024;
      if (j < 5000) {
        float ix1 = fmaxf(bx1, x1[r]), iy1 = fmaxf(by1, y1[r]);
        float ix2 = fminf(bx2, x2[r]), iy2 = fminf(by2, y2[r]);
        float iw = fmaxf(ix2 - ix1, 0.f), ih = fmaxf(iy2 - iy1, 0.f);
        float inter = iw * ih;
        float iou = inter / ((ba + ar[r] - inter) + 1e-9f);
        if (iou > 0.6f || j == pick) s[j] = -1.0f;
      }
    }
    __syncthreads();
  }
}

// ---------------- host launch ----------------
static inline size_t alignup(size_t x) { return (x + 255) & ~(size_t)255; }

extern "C" void kernel_launch(void* const* d_in, const int* in_sizes, int n_in,
                              void* d_out, int out_size, void* d_ws, size_t ws_size,
                              hipStream_t stream) {
  (void)in_sizes; (void)n_in; (void)out_size; (void)ws_size;
  const float* p0 = (const float*)d_in[0];
  const float* p1 = (const float*)d_in[1];
  const float* p2 = (const float*)d_in[2];
  const float* p3 = (const float*)d_in[3];
  const float* p4 = (const float*)d_in[4];
  const float* cls_w   = (const float*)d_in[5];
  const float* cls_b   = (const float*)d_in[6];
  const float* box_w   = (const float*)d_in[7];
  const float* box_b   = (const float*)d_in[8];
  const float* logit_w = (const float*)d_in[9];
  const float* logit_b = (const float*)d_in[10];
  const float* pred_w  = (const float*)d_in[11];
  const float* pred_b  = (const float*)d_in[12];
  const float* ctr_w   = (const float*)d_in[13];
  const float* ctr_b   = (const float*)d_in[14];
  const float* scales  = (const float*)d_in[15];

  char* base = (char*)d_ws;
  size_t off = 0;
  auto take = [&](size_t bytes) { void* p = base + off; off = alignup(off + bytes); return p; };
  float* regb = (float*)take((size_t)4 * 2 * TOTHW * 4);
  float* ctrp = (float*)take((size_t)2 * TOTHW * 4);
  uint32_t* hist = (uint32_t*)take((size_t)40960 * 4);
  int* meta = (int*)take((size_t)40 * 4);
  uint32_t* ctrA = (uint32_t*)take(256);
  uint32_t* ctrB = (uint32_t*)take(256);
  unsigned long long* listA = (unsigned long long*)take((size_t)10 * 1024 * 8);
  float* cbox = (float*)take((size_t)2 * 5000 * 16);
  float* cscr = (float*)take((size_t)2 * 5000 * 4);
  float* ccls = (float*)take((size_t)2 * 5000 * 4);
  unsigned short* wpack = (unsigned short*)take((size_t)9 * 3 * 256 * 256 * 2);
  unsigned short* R1_0 = (unsigned short*)take(SBE * 2);
  unsigned short* R1_1 = (unsigned short*)take(SBE * 2);
  unsigned short* R1_2 = (unsigned short*)take(SBE * 2);
  unsigned short* R2_0 = (unsigned short*)take(SBE * 2);
  unsigned short* R2_1 = (unsigned short*)take(SBE * 2);
  unsigned short* R2_2 = (unsigned short*)take(SBE * 2);
  float* scores = (float*)R2_0;
  unsigned long long* listB = (unsigned long long*)R1_0;
  float* actf = (float*)R1_0;

  const size_t WSTRIDE = (size_t)256 * 2304;

  hipLaunchKernelGGL(k_zero, dim3(168), dim3(256), 0, stream, R1_0, R1_1, R1_2);
  hipLaunchKernelGGL(k_zero, dim3(168), dim3(256), 0, stream, R2_0, R2_1, R2_2);
  hipLaunchKernelGGL(k_prep, dim3(390), dim3(256), 0, stream, p0, p1, p2, p3, p4, R1_0, R1_1, R1_2);

  auto runConv = [&](int epi, const unsigned short* x0, const unsigned short* x1,
                     const unsigned short* x2, const float* bias,
                     unsigned short* y0, unsigned short* y1, unsigned short* y2,
                     float* af, float* sc, int ocblks) {
    MfArgs a;
    a.X0 = x0; a.X1 = x1; a.X2 = x2; a.Wp = wpack; a.bias = bias;
    a.Y0 = y0; a.Y1 = y1; a.Y2 = y2; a.actf = af; a.scores = sc; a.ctrp = ctrp;
    if (epi == 0)      hipLaunchKernelGGL(conv_mfma<0>, dim3(336, ocblks), dim3(256), 0, stream, a);
    else if (epi == 1) hipLaunchKernelGGL(conv_mfma<1>, dim3(336, ocblks), dim3(256), 0, stream, a);
    else               hipLaunchKernelGGL(conv_mfma<2>, dim3(336, ocblks), dim3(256), 0, stream, a);
  };

  // ---- box tower ----
  hipLaunchKernelGGL(k_pack, dim3(256), dim3(256), 0, stream, box_w + 0 * WSTRIDE, wpack);
  runConv(0, R1_0, R1_1, R1_2, box_b + 0,   R2_0, R2_1, R2_2, nullptr, nullptr, 2);
  hipLaunchKernelGGL(k_pack, dim3(256), dim3(256), 0, stream, box_w + 1 * WSTRIDE, wpack);
  runConv(0, R2_0, R2_1, R2_2, box_b + 256, R1_0, R1_1, R1_2, nullptr, nullptr, 2);
  hipLaunchKernelGGL(k_pack, dim3(256), dim3(256), 0, stream, box_w + 2 * WSTRIDE, wpack);
  runConv(0, R1_0, R1_1, R1_2, box_b + 512, R2_0, R2_1, R2_2, nullptr, nullptr, 2);
  hipLaunchKernelGGL(k_pack, dim3(256), dim3(256), 0, stream, box_w + 3 * WSTRIDE, wpack);
  runConv(1, R2_0, R2_1, R2_2, box_b + 768, nullptr, nullptr, nullptr, actf, nullptr, 2);
  hipLaunchKernelGGL(k_head, dim3(NPXB64), dim3(256), 0, stream, actf, ctr_w, ctr_b,
                     pred_w, pred_b, scales, ctrp, regb);

  // ---- cls tower (re-prep input; actf corrupted R1's split layout) ----
  hipLaunchKernelGGL(k_zero, dim3(168), dim3(256), 0, stream, R1_0, R1_1, R1_2);
  hipLaunchKernelGGL(k_prep, dim3(390), dim3(256), 0, stream, p0, p1, p2, p3, p4, R1_0, R1_1, R1_2);
  hipLaunchKernelGGL(k_pack, dim3(256), dim3(256), 0, stream, cls_w + 0 * WSTRIDE, wpack);
  runConv(0, R1_0, R1_1, R1_2, cls_b + 0,   R2_0, R2_1, R2_2, nullptr, nullptr, 2);
  hipLaunchKernelGGL(k_pack, dim3(256), dim3(256), 0, stream, cls_w + 1 * WSTRIDE, wpack);
  runConv(0, R2_0, R2_1, R2_2, cls_b + 256, R1_0, R1_1, R1_2, nullptr, nullptr, 2);
  hipLaunchKernelGGL(k_pack, dim3(256), dim3(256), 0, stream, cls_w + 2 * WSTRIDE, wpack);
  runConv(0, R1_0, R1_1, R1_2, cls_b + 512, R2_0, R2_1, R2_2, nullptr, nullptr, 2);
  hipLaunchKernelGGL(k_pack, dim3(256), dim3(256), 0, stream, cls_w + 3 * WSTRIDE, wpack);
  runConv(0, R2_0, R2_1, R2_2, cls_b + 768, R1_0, R1_1, R1_2, nullptr, nullptr, 2);
  hipLaunchKernelGGL(k_pack, dim3(80), dim3(256), 0, stream, logit_w, wpack);
  runConv(2, R1_0, R1_1, R1_2, logit_b, nullptr, nullptr, nullptr, nullptr, scores, 1);

  // ---- top-k + decode + NMS ----
  hipLaunchKernelGGL(k_init,    dim3(160), dim3(256), 0, stream, hist, ctrA, ctrB);
  hipLaunchKernelGGL(k_hist,    dim3(297, 10), dim3(256), 0, stream, scores, hist);
  hipLaunchKernelGGL(k_select,  dim3(10), dim3(256), 0, stream, hist, meta);
  hipLaunchKernelGGL(k_collect, dim3(297, 10), dim3(256), 0, stream, scores, meta, listA, listB, ctrA, ctrB);
  hipLaunchKernelGGL(k_refine,  dim3(10), dim3(1024), 0, stream, meta, listB, listA, ctrA);
  hipLaunchKernelGGL(k_sortdec, dim3(10), dim3(256), 0, stream, listA, ctrA, regb, cbox, cscr, ccls);
  hipLaunchKernelGGL(k_nms,     dim3(2), dim3(1024), 0, stream, cbox, cscr, ccls, (float*)d_out);
}

// Round 5
// 3267.939 us; speedup vs baseline: 2.6312x; 1.1104x over previous
//
#include <hip/hip_runtime.h>
#include <stdint.h>
#include <math.h>

#define NCLS 80
#define TOTHW 20267

typedef __bf16 bf16x8 __attribute__((ext_vector_type(8)));
typedef float f32x4 __attribute__((ext_vector_type(4)));
typedef short s16x8 __attribute__((ext_vector_type(8)));

static constexpr int cLW[5]    = {152,76,38,19,10};
static constexpr int cLH[5]    = {100,50,25,13,7};
static constexpr int cLHW[5]   = {15200,3800,950,247,70};
static constexpr int cLCUM[5]  = {0,15200,19000,19950,20197};
static constexpr int cLSTR[5]  = {8,16,32,64,128};
// conv px-blocks (128 px of padded plane) per (l,b) plane, cumulative
static constexpr int cCB[11]   = {0,123,246,278,310,319,328,331,334,335,336};
// padded-plane px base (capacity = blocks*128), cumulative
static constexpr int cPBASE[11]= {0,15744,31488,35584,39680,40832,41984,42368,42752,42880,43008};
// interior rows per (l,b) plane, cumulative (for k_prep)
static constexpr int cRCUM[11] = {0,100,200,250,300,325,350,363,376,383,390};
static constexpr int cCPX64[6] = {0,475,594,624,632,635};
#define NPXB64 635
#define SBE 11010048ull   // 43008*256 elements per split buffer

// ---------------- helpers ----------------
__device__ __forceinline__ void split3(float y, unsigned short& h0, unsigned short& h1, unsigned short& h2) {
  __bf16 b0 = (__bf16)y; float f0 = (float)b0;
  float r1 = y - f0;
  __bf16 b1 = (__bf16)r1; float f1 = (float)b1;
  __bf16 b2 = (__bf16)(r1 - f1);
  h0 = __builtin_bit_cast(unsigned short, b0);
  h1 = __builtin_bit_cast(unsigned short, b1);
  h2 = __builtin_bit_cast(unsigned short, b2);
}

__device__ __forceinline__ void lds_hist_add(uint32_t* h, uint32_t bucket) {
  unsigned long long act = __ballot(1);
  int lane = (int)(threadIdx.x & 63u);
  int leader = __ffsll(act) - 1;
  uint32_t lb = (uint32_t)__shfl((int)bucket, leader, 64);
  unsigned long long same = __ballot(bucket == lb);
  if (same == act) {
    if (lane == leader) atomicAdd(&h[bucket], (uint32_t)__popcll(act));
  } else {
    atomicAdd(&h[bucket], 1u);
  }
}

// ---------------- zero borders/gaps of a split-triple region ----------------
__global__ void k_zero(unsigned short* X0, unsigned short* X1, unsigned short* X2) {
  int px = blockIdx.x * 256 + threadIdx.x;
  if (px >= 43008) return;
  int pi = 0;
#pragma unroll
  for (int i = 1; i < 10; i++) if (px >= cPBASE[i]) pi = i;
  const int l = pi >> 1;
  const int p = px - cPBASE[pi];
  const int W = cLW[l], H = cLH[l], PWl = W + 2;
  const int pr = p / PWl, pc = p - pr * PWl;
  if (pr >= 1 && pr <= H && pc >= 1 && pc <= W) return;  // interior: left alone
  s16x8 z = {0,0,0,0,0,0,0,0};
  size_t base = (size_t)px * 256;
#pragma unroll
  for (int k = 0; k < 32; k++) {
    *reinterpret_cast<s16x8*>(X0 + base + k*8) = z;
    *reinterpret_cast<s16x8*>(X1 + base + k*8) = z;
    *reinterpret_cast<s16x8*>(X2 + base + k*8) = z;
  }
}

// ---------------- stage inputs -> padded px-major bf16 splits ----------------
__global__ __launch_bounds__(256)
void k_prep(const float* __restrict__ p0, const float* __restrict__ p1,
            const float* __restrict__ p2, const float* __restrict__ p3,
            const float* __restrict__ p4,
            unsigned short* __restrict__ X0, unsigned short* __restrict__ X1,
            unsigned short* __restrict__ X2) {
  int bx = blockIdx.x;
  int pi = 0;
#pragma unroll
  for (int i = 1; i < 10; i++) if (bx >= cRCUM[i]) pi = i;
  const int h = bx - cRCUM[pi];
  const int l = pi >> 1, bidx = pi & 1;
  const int W = cLW[l], HW = cLHW[l], PWl = W + 2;
  const int PB = cPBASE[pi];
  const float* src;
  if (l == 0) src = p0; else if (l == 1) src = p1; else if (l == 2) src = p2;
  else if (l == 3) src = p3; else src = p4;
  src += (size_t)bidx * 256 * HW;
  const int tid = threadIdx.x;
  __shared__ float tile[64][152];
  for (int c0 = 0; c0 < 256; c0 += 64) {
    {
      int c = tid >> 2, wq = tid & 3;
      for (int w = wq; w < W; w += 4)
        tile[c][w] = src[(size_t)(c0 + c) * HW + h * W + w];
    }
    __syncthreads();
    {
      int c8 = (tid & 7) * 8;
      for (int w = tid >> 3; w < W; w += 32) {
        size_t base = (size_t)(PB + (h + 1) * PWl + (w + 1)) * 256 + c0 + c8;
        unsigned short a0[8], a1[8], a2[8];
#pragma unroll
        for (int j = 0; j < 8; j++) split3(tile[c8 + j][w], a0[j], a1[j], a2[j]);
        *reinterpret_cast<s16x8*>(X0 + base) = *reinterpret_cast<s16x8*>(a0);
        *reinterpret_cast<s16x8*>(X1 + base) = *reinterpret_cast<s16x8*>(a1);
        *reinterpret_cast<s16x8*>(X2 + base) = *reinterpret_cast<s16x8*>(a2);
      }
    }
    __syncthreads();
  }
}

// ---------------- pack weights [Cout][256][3][3] -> [r][s][256][256] bf16 ----------------
__global__ void k_pack(const float* __restrict__ w, unsigned short* __restrict__ wp) {
  const int oc = blockIdx.x, c = threadIdx.x;
#pragma unroll
  for (int r = 0; r < 9; r++) {
    float v = w[((size_t)oc * 256 + c) * 9 + r];
    unsigned short h0, h1, h2;
    split3(v, h0, h1, h2);
    wp[((size_t)(r * 3 + 0) * 256 + oc) * 256 + c] = h0;
    wp[((size_t)(r * 3 + 1) * 256 + oc) * 256 + c] = h1;
    wp[((size_t)(r * 3 + 2) * 256 + oc) * 256 + c] = h2;
  }
}

// ---------------- pack head weights -> wh[r][c][5] ----------------
__global__ void k_packhead(const float* __restrict__ ctw, const float* __restrict__ pdw,
                           float* __restrict__ wh) {
  const int r = blockIdx.x, c = threadIdx.x;
  float* d = &wh[((size_t)r * 256 + c) * 5];
  d[0] = ctw[c * 9 + r];
#pragma unroll
  for (int q = 0; q < 4; q++) d[1 + q] = pdw[(size_t)q * 2304 + c * 9 + r];
}

// ---------------- MFMA conv ----------------
// EPI 0: relu+bias -> write bf16 splits (px-major)
// EPI 1: relu+bias -> write fp32 act px-major [PB+p][256] (for k_head2)
// EPI 2: logits: bias -> sigmoid * ctrp -> threshold -> scores [l][b][cls][hw] + fused hist
struct MfArgs {
  const unsigned short *X0, *X1, *X2;
  const unsigned short *Wp;
  const float* bias;
  unsigned short *Y0, *Y1, *Y2;
  float* actf;
  float* scores;
  const float* ctrp;
  uint32_t* hist;
};

template<int EPI>
__global__ __launch_bounds__(256, 2)
void conv_mfma(MfArgs a) {
  __shared__ __align__(16) unsigned short lds[24576];  // A rows 0..127, B rows 128..255, KP=96
  const int tid = threadIdx.x;
  const int lane = tid & 63;
  const int wid = tid >> 6;

  int bx = blockIdx.x;
  int pi = 0;
#pragma unroll
  for (int i = 1; i < 10; i++) if (bx >= cCB[i]) pi = i;
  const int l = pi >> 1, bidx = pi & 1;
  const int pxb = bx - cCB[pi];
  const int px0 = pxb * 128;
  const int PB = cPBASE[pi];
  const int W = cLW[l], H = cLH[l], HW = cLHW[l], PWl = W + 2;
  const int oc0 = blockIdx.y * 128;

  int row_[2], g_[2];
  int wA[3][2];
#pragma unroll
  for (int d = 0; d < 2; d++) {
    int idx2 = tid + d * 256;
    row_[d] = idx2 >> 2;
    g_[d] = idx2 & 3;
    int rm = (5 * row_[d]) % 12;
#pragma unroll
    for (int s = 0; s < 3; s++) {
      int ch = s * 4 + g_[d] + rm; if (ch >= 12) ch -= 12; if (ch >= 12) ch -= 12;
      wA[s][d] = row_[d] * 96 + ch * 8;
    }
  }

  const int wr = wid >> 1, wc = wid & 1;
  const int kg = lane >> 4, ln15 = lane & 15;
  int fA[4][3], fB[4][3];
#pragma unroll
  for (int mt = 0; mt < 4; mt++) {
    int rowA = wr * 64 + mt * 16 + ln15;
    int rm = (5 * rowA) % 12;
#pragma unroll
    for (int s = 0; s < 3; s++) {
      int ch = s * 4 + kg + rm; if (ch >= 12) ch -= 12; if (ch >= 12) ch -= 12;
      fA[mt][s] = rowA * 96 + ch * 8;
    }
  }
#pragma unroll
  for (int nt = 0; nt < 4; nt++) {
    int rowB = wc * 64 + nt * 16 + ln15;
    int rm = (5 * rowB) % 12;
#pragma unroll
    for (int s = 0; s < 3; s++) {
      int ch = s * 4 + kg + rm; if (ch >= 12) ch -= 12; if (ch >= 12) ch -= 12;
      fB[nt][s] = (128 + rowB) * 96 + ch * 8;
    }
  }

  f32x4 acc[4][4];
#pragma unroll
  for (int mt = 0; mt < 4; mt++)
#pragma unroll
    for (int nt = 0; nt < 4; nt++) acc[mt][nt] = (f32x4){0.f, 0.f, 0.f, 0.f};

  for (int step = 0; step < 72; ++step) {
    const int rr = step >> 3;
    const int c0 = (step & 7) << 5;
    const int dh = rr / 3 - 1, dw = rr - (rr / 3) * 3 - 1;
    const long long OFF = (long long)(PB + px0 + dh * PWl + dw);
    s16x8 ra[6], rb[6];
#pragma unroll
    for (int s = 0; s < 3; s++) {
      const unsigned short* Xs = (s == 0) ? a.X0 : (s == 1) ? a.X1 : a.X2;
      const unsigned short* Ws = a.Wp + (size_t)(rr * 3 + s) * 65536;
#pragma unroll
      for (int d = 0; d < 2; d++) {
        ra[s * 2 + d] = *reinterpret_cast<const s16x8*>(Xs + (OFF + row_[d]) * 256 + c0 + g_[d] * 8);
        rb[s * 2 + d] = *reinterpret_cast<const s16x8*>(Ws + (size_t)(oc0 + row_[d]) * 256 + c0 + g_[d] * 8);
      }
    }
    if (step) __syncthreads();
#pragma unroll
    for (int s = 0; s < 3; s++)
#pragma unroll
      for (int d = 0; d < 2; d++) {
        *reinterpret_cast<s16x8*>(&lds[wA[s][d]]) = ra[s * 2 + d];
        *reinterpret_cast<s16x8*>(&lds[wA[s][d] + 12288]) = rb[s * 2 + d];
      }
    __syncthreads();

    bf16x8 bv[4][3];
#pragma unroll
    for (int nt = 0; nt < 4; nt++)
#pragma unroll
      for (int s = 0; s < 3; s++)
        bv[nt][s] = *reinterpret_cast<const bf16x8*>(&lds[fB[nt][s]]);
#pragma unroll
    for (int mt = 0; mt < 4; mt++) {
      bf16x8 av0 = *reinterpret_cast<const bf16x8*>(&lds[fA[mt][0]]);
      bf16x8 av1 = *reinterpret_cast<const bf16x8*>(&lds[fA[mt][1]]);
      bf16x8 av2 = *reinterpret_cast<const bf16x8*>(&lds[fA[mt][2]]);
#pragma unroll
      for (int nt = 0; nt < 4; nt++) {
        acc[mt][nt] = __builtin_amdgcn_mfma_f32_16x16x32_bf16(av0, bv[nt][0], acc[mt][nt], 0, 0, 0);
        acc[mt][nt] = __builtin_amdgcn_mfma_f32_16x16x32_bf16(av0, bv[nt][1], acc[mt][nt], 0, 0, 0);
        acc[mt][nt] = __builtin_amdgcn_mfma_f32_16x16x32_bf16(av1, bv[nt][0], acc[mt][nt], 0, 0, 0);
        acc[mt][nt] = __builtin_amdgcn_mfma_f32_16x16x32_bf16(av1, bv[nt][1], acc[mt][nt], 0, 0, 0);
        acc[mt][nt] = __builtin_amdgcn_mfma_f32_16x16x32_bf16(av0, bv[nt][2], acc[mt][nt], 0, 0, 0);
        acc[mt][nt] = __builtin_amdgcn_mfma_f32_16x16x32_bf16(av2, bv[nt][0], acc[mt][nt], 0, 0, 0);
      }
    }
  }
  __syncthreads();

  // epilogue
  uint32_t* hh = nullptr;
  if (EPI == 2) {
    hh = reinterpret_cast<uint32_t*>(lds);   // LDS reuse: 4096 bins
    for (int i = tid; i < 4096; i += 256) hh[i] = 0;
    __syncthreads();
  }
#pragma unroll
  for (int mt = 0; mt < 4; mt++) {
#pragma unroll
    for (int i = 0; i < 4; i++) {
      const int pxl = wr * 64 + mt * 16 + (lane >> 4) * 4 + i;
      const int p = px0 + pxl;
      const int pr = p / PWl, pc = p - pr * PWl;
      if (!(pr >= 1 && pr <= H && pc >= 1 && pc <= W)) continue;
      const int hw = (pr - 1) * W + (pc - 1);
#pragma unroll
      for (int nt = 0; nt < 4; nt++) {
        const int oc = oc0 + wc * 64 + nt * 16 + ln15;
        if (EPI == 2) {
          if (oc < NCLS) {
            float y = acc[mt][nt][i] + a.bias[oc];
            float pcs = 1.0f / (1.0f + expf(-y));
            float s = pcs * a.ctrp[2 * cLCUM[l] + bidx * HW + hw];
            s = (s > 0.05f) ? s : 0.f;
            a.scores[(size_t)NCLS * (2 * cLCUM[l] + bidx * HW) + (size_t)oc * HW + hw] = s;
            lds_hist_add(hh, __float_as_uint(s) >> 20);
          }
        } else {
          float y = fmaxf(acc[mt][nt][i] + a.bias[oc], 0.f);
          if (EPI == 0) {
            size_t o = (size_t)(PB + p) * 256 + oc;
            unsigned short h0, h1, h2;
            split3(y, h0, h1, h2);
            a.Y0[o] = h0; a.Y1[o] = h1; a.Y2[o] = h2;
          } else {
            a.actf[(size_t)(PB + p) * 256 + oc] = y;   // px-major fp32
          }
        }
      }
    }
  }
  if (EPI == 2) {
    __syncthreads();
    uint32_t* gh = a.hist + (size_t)(l * 2 + bidx) * 4096;
    for (int i = tid; i < 4096; i += 256) { uint32_t v = hh[i]; if (v) atomicAdd(&gh[i], v); }
  }
}

// ---------------- ctr + reg head: wave-per-px over px-major fp32 act ----------------
__global__ __launch_bounds__(256)
void k_head2(const float* __restrict__ headact, const float* __restrict__ wh,
             const float* __restrict__ ctb, const float* __restrict__ pdb,
             const float* __restrict__ scl,
             float* __restrict__ ctrp, float* __restrict__ regb) {
  __shared__ float swh[11520];
  for (int i = threadIdx.x; i < 11520; i += 256) swh[i] = wh[i];
  int bx = blockIdx.x; int l = 0;
#pragma unroll
  for (int i = 1; i < 5; i++) if (bx >= cCPX64[i]) l = i;
  const int lblk = bx - cCPX64[l];
  const int H = cLH[l], W = cLW[l], HW = cLHW[l]; const int N = 2 * HW;
  const int lane = threadIdx.x & 63;
  const int wv = threadIdx.x >> 6;
  __syncthreads();
  const float bb0 = ctb[0], bb1 = pdb[0], bb2 = pdb[1], bb3 = pdb[2], bb4 = pdb[3];
  const float sc = scl[l];
  const int c4 = lane * 4;
  for (int t = 0; t < 16; ++t) {
    int px = lblk * 64 + wv * 16 + t;
    if (px >= N) break;                       // wave-uniform
    int bb = px / HW; int hw = px - bb * HW; int hh = hw / W; int ww = hw - hh * W;
    const int PB = cPBASE[l * 2 + bb];
    float a0 = 0.f, a1 = 0.f, a2 = 0.f, a3 = 0.f, a4 = 0.f;
#pragma unroll
    for (int r = 0; r < 9; r++) {
      int dh = r / 3 - 1, dw = r % 3 - 1;
      int ih = hh + dh, iw = ww + dw;
      if (!(((unsigned)ih < (unsigned)H) && ((unsigned)iw < (unsigned)W))) continue;
      const float4 x = *reinterpret_cast<const float4*>(
          headact + (size_t)(PB + (ih + 1) * (W + 2) + (iw + 1)) * 256 + c4);
      const float* wr = &swh[(size_t)(r * 256 + c4) * 5];
      a0 = fmaf(x.x, wr[0],  a0); a1 = fmaf(x.x, wr[1],  a1); a2 = fmaf(x.x, wr[2],  a2);
      a3 = fmaf(x.x, wr[3],  a3); a4 = fmaf(x.x, wr[4],  a4);
      a0 = fmaf(x.y, wr[5],  a0); a1 = fmaf(x.y, wr[6],  a1); a2 = fmaf(x.y, wr[7],  a2);
      a3 = fmaf(x.y, wr[8],  a3); a4 = fmaf(x.y, wr[9],  a4);
      a0 = fmaf(x.z, wr[10], a0); a1 = fmaf(x.z, wr[11], a1); a2 = fmaf(x.z, wr[12], a2);
      a3 = fmaf(x.z, wr[13], a3); a4 = fmaf(x.z, wr[14], a4);
      a0 = fmaf(x.w, wr[15], a0); a1 = fmaf(x.w, wr[16], a1); a2 = fmaf(x.w, wr[17], a2);
      a3 = fmaf(x.w, wr[18], a3); a4 = fmaf(x.w, wr[19], a4);
    }
#pragma unroll
    for (int off = 32; off > 0; off >>= 1) {
      a0 += __shfl_xor(a0, off, 64); a1 += __shfl_xor(a1, off, 64); a2 += __shfl_xor(a2, off, 64);
      a3 += __shfl_xor(a3, off, 64); a4 += __shfl_xor(a4, off, 64);
    }
    if (lane == 0) {
      const int gi = 2 * cLCUM[l] + bb * HW + hw;
      ctrp[gi] = 1.0f / (1.0f + expf(-(a0 + bb0)));
      float* rg = regb + (size_t)gi * 4;
      rg[0] = fmaxf((a1 + bb1) * sc, 0.f);
      rg[1] = fmaxf((a2 + bb2) * sc, 0.f);
      rg[2] = fmaxf((a3 + bb3) * sc, 0.f);
      rg[3] = fmaxf((a4 + bb4) * sc, 0.f);
    }
  }
}

// ---------------- top-k pipeline ----------------
__global__ void k_init(uint32_t* __restrict__ hist, uint32_t* __restrict__ ctrA,
                       uint32_t* __restrict__ ctrB) {
  int i = blockIdx.x * blockDim.x + threadIdx.x;
  if (i < 40960) hist[i] = 0;
  if (i < 10) { ctrA[i] = 0; ctrB[i] = 0; }
}

__global__ __launch_bounds__(256)
void k_select(const uint32_t* __restrict__ hist, int* __restrict__ meta) {
  const int sid = blockIdx.x;
  const uint32_t* gh = hist + (size_t)sid * 4096;
  __shared__ uint32_t ps[256];
  uint32_t sum = 0;
  for (int i = 0; i < 16; i++) sum += gh[threadIdx.x * 16 + i];
  ps[threadIdx.x] = sum;
  __syncthreads();
  if (threadIdx.x == 0) {
    uint32_t c = 0; int T = 0, m = 1000;
    for (int ch = 255; ch >= 0; --ch) {
      if (c + ps[ch] >= 1000u) {
        for (int t = ch * 16 + 15; t >= ch * 16; --t) {
          uint32_t hv = gh[t];
          if (c + hv >= 1000u) { T = t; m = (int)(1000u - c); break; }
          c += hv;
        }
        break;
      }
      c += ps[ch];
    }
    meta[sid * 4 + 0] = T;
    meta[sid * 4 + 1] = (int)c;
    meta[sid * 4 + 2] = m;
    meta[sid * 4 + 3] = (int)gh[T];
  }
}

// two-pass block-aggregated collect: 2 global atomics per block (was ~1/wave-iter)
__global__ __launch_bounds__(256)
void k_collect(const float* __restrict__ scores, const int* __restrict__ meta,
               unsigned long long* __restrict__ listA, unsigned long long* __restrict__ listB,
               uint32_t* __restrict__ ctrA, uint32_t* __restrict__ ctrB) {
  const int sid = blockIdx.y; const int l = sid >> 1, b = sid & 1;
  const int HW = cLHW[l]; const int size = NCLS * HW;
  const int base = blockIdx.x * 4096;
  if (base >= size) return;
  const size_t sbase = (size_t)NCLS * (2 * cLCUM[l] + b * HW);
  const float* sb = scores + sbase;
  unsigned long long* lB = listB + sbase;
  unsigned long long* lA = listA + (size_t)sid * 1024;
  const uint32_t T = (uint32_t)meta[sid * 4];
  const int lane = (int)(threadIdx.x & 63u);
  __shared__ uint32_t cA, cB, bA, bB;
  if (threadIdx.x == 0) { cA = 0; cB = 0; }
  __syncthreads();
  uint32_t wa = 0, wb = 0;
  for (int j = 0; j < 16; j++) {
    int i = base + threadIdx.x + j * 256;
    bool inb = (i < size);
    uint32_t bits = inb ? __float_as_uint(sb[i]) : 0u;
    uint32_t bkt = bits >> 20;
    unsigned long long mA = __ballot(inb && bkt > T);
    unsigned long long mB = __ballot(inb && bkt == T);
    if (lane == 0) { wa += (uint32_t)__popcll(mA); wb += (uint32_t)__popcll(mB); }
  }
  if (lane == 0) { if (wa) atomicAdd(&cA, wa); if (wb) atomicAdd(&cB, wb); }
  __syncthreads();
  if (threadIdx.x == 0) {
    bA = cA ? atomicAdd(&ctrA[sid], cA) : 0u;
    bB = cB ? atomicAdd(&ctrB[sid], cB) : 0u;
    cA = 0; cB = 0;
  }
  __syncthreads();
  for (int j = 0; j < 16; j++) {
    int i = base + threadIdx.x + j * 256;
    bool inb = (i < size);
    uint32_t bits = inb ? __float_as_uint(sb[i]) : 0u;
    uint32_t bkt = bits >> 20;
    bool pA = inb && bkt > T;
    bool pB = inb && bkt == T;
    unsigned long long key = 0;
    if (pA || pB) {
      int cls = i / HW; int hw = i - cls * HW;
      uint32_t idx = (uint32_t)(hw * NCLS + cls);
      key = ((unsigned long long)bits << 32) | (unsigned long long)(0xFFFFFFFFu - idx);
    }
    unsigned long long mA = __ballot(pA);
    unsigned long long mB = __ballot(pB);
    unsigned long long lt = (1ull << lane) - 1ull;
    if (mA) {
      int ld = __ffsll(mA) - 1;
      uint32_t wbs = 0;
      if (lane == ld) wbs = atomicAdd(&cA, (uint32_t)__popcll(mA));
      wbs = (uint32_t)__shfl((int)wbs, ld, 64);
      if (pA) {
        uint32_t pos = bA + wbs + (uint32_t)__popcll(mA & lt);
        if (pos < 1024u) lA[pos] = key;
      }
    }
    if (mB) {
      int ld = __ffsll(mB) - 1;
      uint32_t wbs = 0;
      if (lane == ld) wbs = atomicAdd(&cB, (uint32_t)__popcll(mB));
      wbs = (uint32_t)__shfl((int)wbs, ld, 64);
      if (pB) lB[bB + wbs + (uint32_t)__popcll(mB & lt)] = key;
    }
  }
}

__global__ __launch_bounds__(1024)
void k_refine(const int* __restrict__ meta, const unsigned long long* __restrict__ listB,
              unsigned long long* __restrict__ listA, uint32_t* __restrict__ ctrA) {
  const int sid = blockIdx.x; const int l = sid >> 1, b = sid & 1;
  const int HW = cLHW[l];
  const size_t sbase = (size_t)NCLS * (2 * cLCUM[l] + b * HW);
  const unsigned long long* lB = listB + sbase;
  const int nB = meta[sid * 4 + 3];
  int m = meta[sid * 4 + 2];
  __shared__ uint32_t h[256];
  __shared__ unsigned long long sPre;
  __shared__ int sM;
  __shared__ uint32_t sCnt;
  unsigned long long prefix = 0, mask = 0;
  for (int p = 7; p >= 0; --p) {
    for (int i = threadIdx.x; i < 256; i += 1024) h[i] = 0;
    __syncthreads();
    for (int i = threadIdx.x; i < nB; i += 1024) {
      unsigned long long k = lB[i];
      if ((k & mask) == prefix) {
        uint32_t bkt = (uint32_t)((k >> (p * 8)) & 255ull);
        lds_hist_add(h, bkt);
      }
    }
    __syncthreads();
    if (threadIdx.x == 0) {
      uint32_t c = 0; int sel = 0; int mnew = m;
      for (int t = 255; t >= 0; --t) {
        if (c + h[t] >= (uint32_t)m) { sel = t; mnew = m - (int)c; break; }
        c += h[t];
      }
      sPre = prefix | ((unsigned long long)sel << (p * 8));
      sM = mnew;
    }
    __syncthreads();
    prefix = sPre; m = sM;
    mask |= (0xFFull << (p * 8));
    __syncthreads();
  }
  if (threadIdx.x == 0) sCnt = ctrA[sid];
  __syncthreads();
  for (int i = threadIdx.x; i < nB; i += 1024) {
    unsigned long long k = lB[i];
    if (k >= prefix) {
      uint32_t pos = atomicAdd(&sCnt, 1u);
      if (pos < 1024u) listA[(size_t)sid * 1024 + pos] = k;
    }
  }
  __syncthreads();
  if (threadIdx.x == 0) ctrA[sid] = sCnt;
}

__global__ __launch_bounds__(256)
void k_sortdec(const unsigned long long* __restrict__ listA, const uint32_t* __restrict__ ctrA,
               const float* __restrict__ regb, float* __restrict__ cbox,
               float* __restrict__ cscr, float* __restrict__ ccls) {
  const int sid = blockIdx.x; const int l = sid >> 1, b = sid & 1;
  const int HW = cLHW[l], W = cLW[l];
  __shared__ unsigned long long key[1024];
  int n = (int)ctrA[sid]; if (n > 1024) n = 1024;
  for (int i = threadIdx.x; i < 1024; i += 256)
    key[i] = (i < n) ? listA[(size_t)sid * 1024 + i] : 0ull;
  __syncthreads();
  for (int len = 2; len <= 1024; len <<= 1) {
    for (int j = len >> 1; j > 0; j >>= 1) {
      for (int t = threadIdx.x; t < 512; t += 256) {
        int i = ((t & ~(j - 1)) << 1) | (t & (j - 1));
        int pp = i | j;
        unsigned long long a = key[i], bq = key[pp];
        bool desc = ((i & len) == 0);
        if ((a < bq) == desc) { key[i] = bq; key[pp] = a; }
      }
      __syncthreads();
    }
  }
  for (int r = threadIdx.x; r < 1000; r += 256) {
    unsigned long long k = key[r];
    uint32_t bits = (uint32_t)(k >> 32);
    uint32_t idx = 0xFFFFFFFFu - (uint32_t)(k & 0xFFFFFFFFull);
    float val = __uint_as_float(bits);
    float sc = sqrtf(fmaxf(val, 1e-12f));
    int cls = (int)(idx % NCLS); int loc = (int)(idx / NCLS);
    int hh = loc / W; int ww = loc - hh * W;
    float cx = (float)(ww * cLSTR[l] + (cLSTR[l] >> 1));
    float cy = (float)(hh * cLSTR[l] + (cLSTR[l] >> 1));
    const float* rg = regb + (size_t)(2 * cLCUM[l] + b * HW + loc) * 4;
    int slot = b * 5000 + l * 1000 + r;
    cbox[slot * 4 + 0] = cx - rg[0];
    cbox[slot * 4 + 1] = cy - rg[1];
    cbox[slot * 4 + 2] = cx + rg[2];
    cbox[slot * 4 + 3] = cy + rg[3];
    cscr[slot] = sc;
    ccls[slot] = (float)cls;
  }
}

// ---------------- NMS ----------------
__global__ __launch_bounds__(1024)
void k_nms(const float* __restrict__ cbox, const float* __restrict__ cscr,
           const float* __restrict__ ccls, float* __restrict__ out) {
  const int b = blockIdx.x;
  const int tid = threadIdx.x;
  __shared__ float s[5000];
  __shared__ float wv[16]; __shared__ int wi[16];
  __shared__ float bbx[5]; __shared__ int sBi; __shared__ float sBv;
  float x1[5], y1[5], x2[5], y2[5], ar[5];
#pragma unroll
  for (int r = 0; r < 5; r++) {
    int j = tid + r * 1024;
    if (j < 5000) {
      const float4 bx = *reinterpret_cast<const float4*>(cbox + ((size_t)b * 5000 + j) * 4);
      float off = ccls[b * 5000 + j] * 10000.0f;
      x1[r] = bx.x + off; y1[r] = bx.y + off; x2[r] = bx.z + off; y2[r] = bx.w + off;
      ar[r] = (x2[r] - x1[r]) * (y2[r] - y1[r]);
      s[j] = cscr[b * 5000 + j];
    }
  }
  __syncthreads();
  for (int it = 0; it < 100; ++it) {
    float best = -1e30f; int bi = 0x7FFFFFFF;
#pragma unroll
    for (int r = 0; r < 5; r++) {
      int j = tid + r * 1024;
      if (j < 5000) {
        float v = s[j];
        if (v > best || (v == best && j < bi)) { best = v; bi = j; }
      }
    }
    for (int o = 32; o > 0; o >>= 1) {
      float ov = __shfl_down(best, o, 64); int oi = __shfl_down(bi, o, 64);
      if (ov > best || (ov == best && oi < bi)) { best = ov; bi = oi; }
    }
    if ((tid & 63) == 0) { wv[tid >> 6] = best; wi[tid >> 6] = bi; }
    __syncthreads();
    if (tid < 64) {
      float v = (tid < 16) ? wv[tid] : -1e30f; int ix = (tid < 16) ? wi[tid] : 0x7FFFFFFF;
      for (int o = 8; o > 0; o >>= 1) {
        float ov = __shfl_down(v, o, 64); int oi = __shfl_down(ix, o, 64);
        if (ov > v || (ov == v && oi < ix)) { v = ov; ix = oi; }
      }
      if (tid == 0) { sBi = ix; sBv = v; }
    }
    __syncthreads();
    const int pick = sBi; const float pv = sBv;
    if (tid == (pick & 1023)) {
      const int r = pick >> 10;
      bbx[0] = x1[r]; bbx[1] = y1[r]; bbx[2] = x2[r]; bbx[3] = y2[r]; bbx[4] = ar[r];
      float* orow = out + ((size_t)b * 100 + it) * 6;
      if (pv > 0.f) {
        const float4 obx = *reinterpret_cast<const float4*>(cbox + ((size_t)b * 5000 + pick) * 4);
        orow[0] = obx.x; orow[1] = obx.y; orow[2] = obx.z; orow[3] = obx.w;
        orow[4] = pv; orow[5] = ccls[b * 5000 + pick];
      } else {
        orow[0] = 0.f; orow[1] = 0.f; orow[2] = 0.f; orow[3] = 0.f; orow[4] = 0.f; orow[5] = 0.f;
      }
    }
    __syncthreads();
    const float bx1 = bbx[0], by1 = bbx[1], bx2 = bbx[2], by2 = bbx[3], ba = bbx[4];
#pragma unroll
    for (int r = 0; r < 5; r++) {
      int j = tid + r * 1024;
      if (j < 5000) {
        float ix1 = fmaxf(bx1, x1[r]), iy1 = fmaxf(by1, y1[r]);
        float ix2 = fminf(bx2, x2[r]), iy2 = fminf(by2, y2[r]);
        float iw = fmaxf(ix2 - ix1, 0.f), ih = fmaxf(iy2 - iy1, 0.f);
        float inter = iw * ih;
        float iou = inter / ((ba + ar[r] - inter) + 1e-9f);
        if (iou > 0.6f || j == pick) s[j] = -1.0f;
      }
    }
    __syncthreads();
  }
}

// ---------------- host launch ----------------
static inline size_t alignup(size_t x) { return (x + 255) & ~(size_t)255; }

extern "C" void kernel_launch(void* const* d_in, const int* in_sizes, int n_in,
                              void* d_out, int out_size, void* d_ws, size_t ws_size,
                              hipStream_t stream) {
  (void)in_sizes; (void)n_in; (void)out_size; (void)ws_size;
  const float* p0 = (const float*)d_in[0];
  const float* p1 = (const float*)d_in[1];
  const float* p2 = (const float*)d_in[2];
  const float* p3 = (const float*)d_in[3];
  const float* p4 = (const float*)d_in[4];
  const float* cls_w   = (const float*)d_in[5];
  const float* cls_b   = (const float*)d_in[6];
  const float* box_w   = (const float*)d_in[7];
  const float* box_b   = (const float*)d_in[8];
  const float* logit_w = (const float*)d_in[9];
  const float* logit_b = (const float*)d_in[10];
  const float* pred_w  = (const float*)d_in[11];
  const float* pred_b  = (const float*)d_in[12];
  const float* ctr_w   = (const float*)d_in[13];
  const float* ctr_b   = (const float*)d_in[14];
  const float* scales  = (const float*)d_in[15];

  char* base = (char*)d_ws;
  size_t off = 0;
  auto take = [&](size_t bytes) { void* p = base + off; off = alignup(off + bytes); return p; };
  float* regb = (float*)take((size_t)4 * 2 * TOTHW * 4);
  float* ctrp = (float*)take((size_t)2 * TOTHW * 4);
  uint32_t* hist = (uint32_t*)take((size_t)40960 * 4);
  int* meta = (int*)take((size_t)40 * 4);
  uint32_t* ctrA = (uint32_t*)take(256);
  uint32_t* ctrB = (uint32_t*)take(256);
  unsigned long long* listA = (unsigned long long*)take((size_t)10 * 1024 * 8);
  float* cbox = (float*)take((size_t)2 * 5000 * 16);
  float* cscr = (float*)take((size_t)2 * 5000 * 4);
  float* ccls = (float*)take((size_t)2 * 5000 * 4);
  float* wh   = (float*)take((size_t)9 * 256 * 5 * 4);
  unsigned short* wpack = (unsigned short*)take((size_t)9 * 3 * 256 * 256 * 2);
  unsigned short* R1_0 = (unsigned short*)take(SBE * 2);
  unsigned short* R1_1 = (unsigned short*)take(SBE * 2);
  unsigned short* R1_2 = (unsigned short*)take(SBE * 2);
  unsigned short* R2_0 = (unsigned short*)take(SBE * 2);
  unsigned short* R2_1 = (unsigned short*)take(SBE * 2);
  unsigned short* R2_2 = (unsigned short*)take(SBE * 2);
  float* scores = (float*)R2_0;                      // free when logits conv runs
  unsigned long long* listB = (unsigned long long*)R1_0;
  float* headact = (float*)R1_0;                     // 43008*256*4 B == R1_0+R1_1 exactly

  const size_t WSTRIDE = (size_t)256 * 2304;

  hipLaunchKernelGGL(k_init, dim3(160), dim3(256), 0, stream, hist, ctrA, ctrB);
  hipLaunchKernelGGL(k_packhead, dim3(9), dim3(256), 0, stream, ctr_w, pred_w, wh);
  hipLaunchKernelGGL(k_zero, dim3(168), dim3(256), 0, stream, R1_0, R1_1, R1_2);
  hipLaunchKernelGGL(k_zero, dim3(168), dim3(256), 0, stream, R2_0, R2_1, R2_2);
  hipLaunchKernelGGL(k_prep, dim3(390), dim3(256), 0, stream, p0, p1, p2, p3, p4, R1_0, R1_1, R1_2);

  auto runConv = [&](int epi, const unsigned short* x0, const unsigned short* x1,
                     const unsigned short* x2, const float* bias,
                     unsigned short* y0, unsigned short* y1, unsigned short* y2,
                     float* af, float* sc, int ocblks) {
    MfArgs a;
    a.X0 = x0; a.X1 = x1; a.X2 = x2; a.Wp = wpack; a.bias = bias;
    a.Y0 = y0; a.Y1 = y1; a.Y2 = y2; a.actf = af; a.scores = sc; a.ctrp = ctrp;
    a.hist = hist;
    if (epi == 0)      hipLaunchKernelGGL(conv_mfma<0>, dim3(336, ocblks), dim3(256), 0, stream, a);
    else if (epi == 1) hipLaunchKernelGGL(conv_mfma<1>, dim3(336, ocblks), dim3(256), 0, stream, a);
    else               hipLaunchKernelGGL(conv_mfma<2>, dim3(336, ocblks), dim3(256), 0, stream, a);
  };

  // ---- box tower ----
  hipLaunchKernelGGL(k_pack, dim3(256), dim3(256), 0, stream, box_w + 0 * WSTRIDE, wpack);
  runConv(0, R1_0, R1_1, R1_2, box_b + 0,   R2_0, R2_1, R2_2, nullptr, nullptr, 2);
  hipLaunchKernelGGL(k_pack, dim3(256), dim3(256), 0, stream, box_w + 1 * WSTRIDE, wpack);
  runConv(0, R2_0, R2_1, R2_2, box_b + 256, R1_0, R1_1, R1_2, nullptr, nullptr, 2);
  hipLaunchKernelGGL(k_pack, dim3(256), dim3(256), 0, stream, box_w + 2 * WSTRIDE, wpack);
  runConv(0, R1_0, R1_1, R1_2, box_b + 512, R2_0, R2_1, R2_2, nullptr, nullptr, 2);
  hipLaunchKernelGGL(k_pack, dim3(256), dim3(256), 0, stream, box_w + 3 * WSTRIDE, wpack);
  runConv(1, R2_0, R2_1, R2_2, box_b + 768, nullptr, nullptr, nullptr, headact, nullptr, 2);
  hipLaunchKernelGGL(k_head2, dim3(NPXB64), dim3(256), 0, stream, headact, wh, ctr_b,
                     pred_b, scales, ctrp, regb);

  // ---- cls tower (re-prep input; headact overwrote R1_0/R1_1) ----
  hipLaunchKernelGGL(k_zero, dim3(168), dim3(256), 0, stream, R1_0, R1_1, R1_2);
  hipLaunchKernelGGL(k_prep, dim3(390), dim3(256), 0, stream, p0, p1, p2, p3, p4, R1_0, R1_1, R1_2);
  hipLaunchKernelGGL(k_pack, dim3(256), dim3(256), 0, stream, cls_w + 0 * WSTRIDE, wpack);
  runConv(0, R1_0, R1_1, R1_2, cls_b + 0,   R2_0, R2_1, R2_2, nullptr, nullptr, 2);
  hipLaunchKernelGGL(k_pack, dim3(256), dim3(256), 0, stream, cls_w + 1 * WSTRIDE, wpack);
  runConv(0, R2_0, R2_1, R2_2, cls_b + 256, R1_0, R1_1, R1_2, nullptr, nullptr, 2);
  hipLaunchKernelGGL(k_pack, dim3(256), dim3(256), 0, stream, cls_w + 2 * WSTRIDE, wpack);
  runConv(0, R1_0, R1_1, R1_2, cls_b + 512, R2_0, R2_1, R2_2, nullptr, nullptr, 2);
  hipLaunchKernelGGL(k_pack, dim3(256), dim3(256), 0, stream, cls_w + 3 * WSTRIDE, wpack);
  runConv(0, R2_0, R2_1, R2_2, cls_b + 768, R1_0, R1_1, R1_2, nullptr, nullptr, 2);
  hipLaunchKernelGGL(k_pack, dim3(80), dim3(256), 0, stream, logit_w, wpack);
  runConv(2, R1_0, R1_1, R1_2, logit_b, nullptr, nullptr, nullptr, nullptr, scores, 1);

  // ---- top-k + decode + NMS ----
  hipLaunchKernelGGL(k_select,  dim3(10), dim3(256), 0, stream, hist, meta);
  hipLaunchKernelGGL(k_collect, dim3(297, 10), dim3(256), 0, stream, scores, meta, listA, listB, ctrA, ctrB);
  hipLaunchKernelGGL(k_refine,  dim3(10), dim3(1024), 0, stream, meta, listB, listA, ctrA);
  hipLaunchKernelGGL(k_sortdec, dim3(10), dim3(256), 0, stream, listA, ctrA, regb, cbox, cscr, ccls);
  hipLaunchKernelGGL(k_nms,     dim3(2), dim3(1024), 0, stream, cbox, cscr, ccls, (float*)d_out);
}

// Round 6
// 2245.445 us; speedup vs baseline: 3.8293x; 1.4554x over previous
//
#include <hip/hip_runtime.h>
#include <stdint.h>
#include <math.h>

#define NCLS 80
#define TOTHW 20267

typedef _Float16 f16x8 __attribute__((ext_vector_type(8)));
typedef float f32x4 __attribute__((ext_vector_type(4)));
typedef short s16x8 __attribute__((ext_vector_type(8)));

static constexpr int cLW[5]    = {152,76,38,19,10};
static constexpr int cLH[5]    = {100,50,25,13,7};
static constexpr int cLHW[5]   = {15200,3800,950,247,70};
static constexpr int cLCUM[5]  = {0,15200,19000,19950,20197};
static constexpr int cLSTR[5]  = {8,16,32,64,128};
// conv px-blocks (128 px of padded plane) per (l,b) plane, cumulative
static constexpr int cCB[11]   = {0,123,246,278,310,319,328,331,334,335,336};
// padded-plane px base (capacity = blocks*128), cumulative
static constexpr int cPBASE[11]= {0,15744,31488,35584,39680,40832,41984,42368,42752,42880,43008};
// interior rows per (l,b) plane, cumulative (for k_prep)
static constexpr int cRCUM[11] = {0,100,200,250,300,325,350,363,376,383,390};
static constexpr int cCPX64[6] = {0,475,594,624,632,635};
#define NPXB64 635
#define SBE 11010048ull   // 43008*256 elements per split buffer

// ---------------- helpers ----------------
// fp32 -> fp16 pair with scaled residual: x ~= h0 + h1 * 2^-11  (error <= 2^-24 |x|)
__device__ __forceinline__ void split2(float y, unsigned short& h0, unsigned short& h1) {
  _Float16 b0 = (_Float16)y;
  float f0 = (float)b0;
  _Float16 b1 = (_Float16)((y - f0) * 2048.0f);
  h0 = __builtin_bit_cast(unsigned short, b0);
  h1 = __builtin_bit_cast(unsigned short, b1);
}

__device__ __forceinline__ void lds_hist_add(uint32_t* h, uint32_t bucket) {
  unsigned long long act = __ballot(1);
  int lane = (int)(threadIdx.x & 63u);
  int leader = __ffsll(act) - 1;
  uint32_t lb = (uint32_t)__shfl((int)bucket, leader, 64);
  unsigned long long same = __ballot(bucket == lb);
  if (same == act) {
    if (lane == leader) atomicAdd(&h[bucket], (uint32_t)__popcll(act));
  } else {
    atomicAdd(&h[bucket], 1u);
  }
}

// ---------------- zero borders/gaps of a split-pair region ----------------
__global__ void k_zero(unsigned short* X0, unsigned short* X1) {
  int px = blockIdx.x * 256 + threadIdx.x;
  if (px >= 43008) return;
  int pi = 0;
#pragma unroll
  for (int i = 1; i < 10; i++) if (px >= cPBASE[i]) pi = i;
  const int l = pi >> 1;
  const int p = px - cPBASE[pi];
  const int W = cLW[l], H = cLH[l], PWl = W + 2;
  const int pr = p / PWl, pc = p - pr * PWl;
  if (pr >= 1 && pr <= H && pc >= 1 && pc <= W) return;  // interior: left alone
  s16x8 z = {0,0,0,0,0,0,0,0};
  size_t base = (size_t)px * 256;
#pragma unroll
  for (int k = 0; k < 32; k++) {
    *reinterpret_cast<s16x8*>(X0 + base + k*8) = z;
    *reinterpret_cast<s16x8*>(X1 + base + k*8) = z;
  }
}

// ---------------- stage inputs -> padded px-major fp16 splits ----------------
__global__ __launch_bounds__(256)
void k_prep(const float* __restrict__ p0, const float* __restrict__ p1,
            const float* __restrict__ p2, const float* __restrict__ p3,
            const float* __restrict__ p4,
            unsigned short* __restrict__ X0, unsigned short* __restrict__ X1) {
  int bx = blockIdx.x;
  int pi = 0;
#pragma unroll
  for (int i = 1; i < 10; i++) if (bx >= cRCUM[i]) pi = i;
  const int h = bx - cRCUM[pi];
  const int l = pi >> 1, bidx = pi & 1;
  const int W = cLW[l], HW = cLHW[l], PWl = W + 2;
  const int PB = cPBASE[pi];
  const float* src;
  if (l == 0) src = p0; else if (l == 1) src = p1; else if (l == 2) src = p2;
  else if (l == 3) src = p3; else src = p4;
  src += (size_t)bidx * 256 * HW;
  const int tid = threadIdx.x;
  __shared__ float tile[64][152];
  for (int c0 = 0; c0 < 256; c0 += 64) {
    {
      int c = tid >> 2, wq = tid & 3;
      for (int w = wq; w < W; w += 4)
        tile[c][w] = src[(size_t)(c0 + c) * HW + h * W + w];
    }
    __syncthreads();
    {
      int c8 = (tid & 7) * 8;
      for (int w = tid >> 3; w < W; w += 32) {
        size_t base = (size_t)(PB + (h + 1) * PWl + (w + 1)) * 256 + c0 + c8;
        unsigned short a0[8], a1[8];
#pragma unroll
        for (int j = 0; j < 8; j++) split2(tile[c8 + j][w], a0[j], a1[j]);
        *reinterpret_cast<s16x8*>(X0 + base) = *reinterpret_cast<s16x8*>(a0);
        *reinterpret_cast<s16x8*>(X1 + base) = *reinterpret_cast<s16x8*>(a1);
      }
    }
    __syncthreads();
  }
}

// ---------------- pack weights [Cout][256][3][3] -> [r][s][256][256] fp16 ----------------
__global__ void k_pack(const float* __restrict__ w, unsigned short* __restrict__ wp) {
  const int oc = blockIdx.x, c = threadIdx.x;
#pragma unroll
  for (int r = 0; r < 9; r++) {
    float v = w[((size_t)oc * 256 + c) * 9 + r];
    unsigned short h0, h1;
    split2(v, h0, h1);
    wp[((size_t)(r * 2 + 0) * 256 + oc) * 256 + c] = h0;
    wp[((size_t)(r * 2 + 1) * 256 + oc) * 256 + c] = h1;
  }
}

// ---------------- pack head weights -> wh[r][c][5] ----------------
__global__ void k_packhead(const float* __restrict__ ctw, const float* __restrict__ pdw,
                           float* __restrict__ wh) {
  const int r = blockIdx.x, c = threadIdx.x;
  float* d = &wh[((size_t)r * 256 + c) * 5];
  d[0] = ctw[c * 9 + r];
#pragma unroll
  for (int q = 0; q < 4; q++) d[1 + q] = pdw[(size_t)q * 2304 + c * 9 + r];
}

// ---------------- MFMA conv (fp16 split-2, scaled residual) ----------------
// EPI 0: relu+bias -> write fp16 splits (px-major)
// EPI 1: relu+bias -> write fp32 act px-major [PB+p][256] (for k_head2)
// EPI 2: logits: bias -> sigmoid * ctrp -> threshold -> scores [l][b][cls][hw] + fused hist
struct MfArgs {
  const unsigned short *X0, *X1;
  const unsigned short *Wp;
  const float* bias;
  unsigned short *Y0, *Y1;
  float* actf;
  float* scores;
  const float* ctrp;
  uint32_t* hist;
};

template<int EPI>
__global__ __launch_bounds__(256, 2)
void conv_mfma(MfArgs a) {
  // KP=72 shorts/row (stride 36 dwords == 4 mod 32 -> conflict-free b128)
  __shared__ __align__(16) unsigned short lds[18432];  // A rows [0,128) ; B at +9216
  const int tid = threadIdx.x;
  const int lane = tid & 63;
  const int wid = tid >> 6;

  // XCD-chunked bijective swizzle; oc-pairs of same px window adjacent (same XCD L2)
  const int nwg = (EPI == 2) ? 336 : 672;
  const int id = blockIdx.x;
  const int w = (id & 7) * (nwg >> 3) + (id >> 3);
  const int oc0 = (EPI == 2) ? 0 : (w & 1) * 128;
  int bx = (EPI == 2) ? w : (w >> 1);

  int pi = 0;
#pragma unroll
  for (int i = 1; i < 10; i++) if (bx >= cCB[i]) pi = i;
  const int l = pi >> 1, bidx = pi & 1;
  const int pxb = bx - cCB[pi];
  const int px0 = pxb * 128;
  const int PB = cPBASE[pi];
  const int W = cLW[l], H = cLH[l], HW = cLHW[l], PWl = W + 2;

  // staging mapping: slot d in {0,1}: idx2 = tid + d*256 -> row (0..127), g (0..3)
  int row_[2], g_[2];
#pragma unroll
  for (int d = 0; d < 2; d++) {
    int idx2 = tid + d * 256;
    row_[d] = idx2 >> 2;
    g_[d] = idx2 & 3;
  }

  const int wr = wid >> 1, wc = wid & 1;
  const int kg = lane >> 4, ln15 = lane & 15;
  int fA[4], fB[4];   // split-0 offsets; split-1 = +32 shorts
#pragma unroll
  for (int mt = 0; mt < 4; mt++) fA[mt] = (wr * 64 + mt * 16 + ln15) * 72 + kg * 8;
#pragma unroll
  for (int nt = 0; nt < 4; nt++) fB[nt] = 9216 + (wc * 64 + nt * 16 + ln15) * 72 + kg * 8;

  f32x4 acc0[4][4], acc1[4][4];
#pragma unroll
  for (int mt = 0; mt < 4; mt++)
#pragma unroll
    for (int nt = 0; nt < 4; nt++) {
      acc0[mt][nt] = (f32x4){0.f, 0.f, 0.f, 0.f};
      acc1[mt][nt] = (f32x4){0.f, 0.f, 0.f, 0.f};
    }

  s16x8 ra[4], rb[4];   // [s*2+d]
  auto loadstep = [&](int step) {
    const int rr = step >> 3;
    const int c0 = (step & 7) << 5;
    const int dh = rr / 3 - 1, dw = rr - (rr / 3) * 3 - 1;
    const long long OFF = (long long)(PB + px0 + dh * PWl + dw);
#pragma unroll
    for (int s = 0; s < 2; s++) {
      const unsigned short* Xs = (s == 0) ? a.X0 : a.X1;
      const unsigned short* Ws = a.Wp + (size_t)(rr * 2 + s) * 65536;
#pragma unroll
      for (int d = 0; d < 2; d++) {
        ra[s * 2 + d] = *reinterpret_cast<const s16x8*>(Xs + (OFF + row_[d]) * 256 + c0 + g_[d] * 8);
        rb[s * 2 + d] = *reinterpret_cast<const s16x8*>(Ws + (size_t)(oc0 + row_[d]) * 256 + c0 + g_[d] * 8);
      }
    }
  };

  loadstep(0);
  for (int step = 0; step < 72; ++step) {
    if (step) __syncthreads();     // frag reads of prev step done before overwrite
#pragma unroll
    for (int s = 0; s < 2; s++)
#pragma unroll
      for (int d = 0; d < 2; d++) {
        const int o = row_[d] * 72 + (s * 4 + g_[d]) * 8;
        *reinterpret_cast<s16x8*>(&lds[o]) = ra[s * 2 + d];
        *reinterpret_cast<s16x8*>(&lds[o + 9216]) = rb[s * 2 + d];
      }
    __syncthreads();
    if (step != 71) loadstep(step + 1);   // in flight under MFMA below

    f16x8 bv[4][2];
#pragma unroll
    for (int nt = 0; nt < 4; nt++) {
      bv[nt][0] = *reinterpret_cast<const f16x8*>(&lds[fB[nt]]);
      bv[nt][1] = *reinterpret_cast<const f16x8*>(&lds[fB[nt] + 32]);
    }
#pragma unroll
    for (int mt = 0; mt < 4; mt++) {
      f16x8 av0 = *reinterpret_cast<const f16x8*>(&lds[fA[mt]]);
      f16x8 av1 = *reinterpret_cast<const f16x8*>(&lds[fA[mt] + 32]);
#pragma unroll
      for (int nt = 0; nt < 4; nt++) {
        acc0[mt][nt] = __builtin_amdgcn_mfma_f32_16x16x32_f16(av0, bv[nt][0], acc0[mt][nt], 0, 0, 0);
        acc1[mt][nt] = __builtin_amdgcn_mfma_f32_16x16x32_f16(av0, bv[nt][1], acc1[mt][nt], 0, 0, 0);
        acc1[mt][nt] = __builtin_amdgcn_mfma_f32_16x16x32_f16(av1, bv[nt][0], acc1[mt][nt], 0, 0, 0);
      }
    }
  }
  __syncthreads();

  // epilogue
  uint32_t* hh = nullptr;
  if (EPI == 2) {
    hh = reinterpret_cast<uint32_t*>(lds);   // LDS reuse: 4096 bins (16 KB)
    for (int i = tid; i < 4096; i += 256) hh[i] = 0;
    __syncthreads();
  }
#pragma unroll
  for (int mt = 0; mt < 4; mt++) {
#pragma unroll
    for (int i = 0; i < 4; i++) {
      const int pxl = wr * 64 + mt * 16 + (lane >> 4) * 4 + i;
      const int p = px0 + pxl;
      const int pr = p / PWl, pc = p - pr * PWl;
      if (!(pr >= 1 && pr <= H && pc >= 1 && pc <= W)) continue;
      const int hw = (pr - 1) * W + (pc - 1);
#pragma unroll
      for (int nt = 0; nt < 4; nt++) {
        const int oc = oc0 + wc * 64 + nt * 16 + ln15;
        const float v = acc0[mt][nt][i] + acc1[mt][nt][i] * 4.8828125e-4f;  // + acc01*2^-11
        if (EPI == 2) {
          if (oc < NCLS) {
            float y = v + a.bias[oc];
            float pcs = 1.0f / (1.0f + expf(-y));
            float s = pcs * a.ctrp[2 * cLCUM[l] + bidx * HW + hw];
            s = (s > 0.05f) ? s : 0.f;
            a.scores[(size_t)NCLS * (2 * cLCUM[l] + bidx * HW) + (size_t)oc * HW + hw] = s;
            lds_hist_add(hh, __float_as_uint(s) >> 20);
          }
        } else {
          float y = fmaxf(v + a.bias[oc], 0.f);
          if (EPI == 0) {
            size_t o = (size_t)(PB + p) * 256 + oc;
            unsigned short h0, h1;
            split2(y, h0, h1);
            a.Y0[o] = h0; a.Y1[o] = h1;
          } else {
            a.actf[(size_t)(PB + p) * 256 + oc] = y;   // px-major fp32
          }
        }
      }
    }
  }
  if (EPI == 2) {
    __syncthreads();
    uint32_t* gh = a.hist + (size_t)(l * 2 + bidx) * 4096;
    for (int i = tid; i < 4096; i += 256) { uint32_t v = hh[i]; if (v) atomicAdd(&gh[i], v); }
  }
}

// ---------------- ctr + reg head: wave-per-px over px-major fp32 act ----------------
__global__ __launch_bounds__(256)
void k_head2(const float* __restrict__ headact, const float* __restrict__ wh,
             const float* __restrict__ ctb, const float* __restrict__ pdb,
             const float* __restrict__ scl,
             float* __restrict__ ctrp, float* __restrict__ regb) {
  __shared__ float swh[11520];
  for (int i = threadIdx.x; i < 11520; i += 256) swh[i] = wh[i];
  int bx = blockIdx.x; int l = 0;
#pragma unroll
  for (int i = 1; i < 5; i++) if (bx >= cCPX64[i]) l = i;
  const int lblk = bx - cCPX64[l];
  const int H = cLH[l], W = cLW[l], HW = cLHW[l]; const int N = 2 * HW;
  const int lane = threadIdx.x & 63;
  const int wv = threadIdx.x >> 6;
  __syncthreads();
  const float bb0 = ctb[0], bb1 = pdb[0], bb2 = pdb[1], bb3 = pdb[2], bb4 = pdb[3];
  const float sc = scl[l];
  const int c4 = lane * 4;
  for (int t = 0; t < 16; ++t) {
    int px = lblk * 64 + wv * 16 + t;
    if (px >= N) break;                       // wave-uniform
    int bb = px / HW; int hw = px - bb * HW; int hh = hw / W; int ww = hw - hh * W;
    const int PB = cPBASE[l * 2 + bb];
    float a0 = 0.f, a1 = 0.f, a2 = 0.f, a3 = 0.f, a4 = 0.f;
#pragma unroll
    for (int r = 0; r < 9; r++) {
      int dh = r / 3 - 1, dw = r % 3 - 1;
      int ih = hh + dh, iw = ww + dw;
      if (!(((unsigned)ih < (unsigned)H) && ((unsigned)iw < (unsigned)W))) continue;
      const float4 x = *reinterpret_cast<const float4*>(
          headact + (size_t)(PB + (ih + 1) * (W + 2) + (iw + 1)) * 256 + c4);
      const float* wr = &swh[(size_t)(r * 256 + c4) * 5];
      a0 = fmaf(x.x, wr[0],  a0); a1 = fmaf(x.x, wr[1],  a1); a2 = fmaf(x.x, wr[2],  a2);
      a3 = fmaf(x.x, wr[3],  a3); a4 = fmaf(x.x, wr[4],  a4);
      a0 = fmaf(x.y, wr[5],  a0); a1 = fmaf(x.y, wr[6],  a1); a2 = fmaf(x.y, wr[7],  a2);
      a3 = fmaf(x.y, wr[8],  a3); a4 = fmaf(x.y, wr[9],  a4);
      a0 = fmaf(x.z, wr[10], a0); a1 = fmaf(x.z, wr[11], a1); a2 = fmaf(x.z, wr[12], a2);
      a3 = fmaf(x.z, wr[13], a3); a4 = fmaf(x.z, wr[14], a4);
      a0 = fmaf(x.w, wr[15], a0); a1 = fmaf(x.w, wr[16], a1); a2 = fmaf(x.w, wr[17], a2);
      a3 = fmaf(x.w, wr[18], a3); a4 = fmaf(x.w, wr[19], a4);
    }
#pragma unroll
    for (int off = 32; off > 0; off >>= 1) {
      a0 += __shfl_xor(a0, off, 64); a1 += __shfl_xor(a1, off, 64); a2 += __shfl_xor(a2, off, 64);
      a3 += __shfl_xor(a3, off, 64); a4 += __shfl_xor(a4, off, 64);
    }
    if (lane == 0) {
      const int gi = 2 * cLCUM[l] + bb * HW + hw;
      ctrp[gi] = 1.0f / (1.0f + expf(-(a0 + bb0)));
      float* rg = regb + (size_t)gi * 4;
      rg[0] = fmaxf((a1 + bb1) * sc, 0.f);
      rg[1] = fmaxf((a2 + bb2) * sc, 0.f);
      rg[2] = fmaxf((a3 + bb3) * sc, 0.f);
      rg[3] = fmaxf((a4 + bb4) * sc, 0.f);
    }
  }
}

// ---------------- top-k pipeline ----------------
__global__ void k_init(uint32_t* __restrict__ hist, uint32_t* __restrict__ ctrA,
                       uint32_t* __restrict__ ctrB) {
  int i = blockIdx.x * blockDim.x + threadIdx.x;
  if (i < 40960) hist[i] = 0;
  if (i < 10) { ctrA[i] = 0; ctrB[i] = 0; }
}

__global__ __launch_bounds__(256)
void k_select(const uint32_t* __restrict__ hist, int* __restrict__ meta) {
  const int sid = blockIdx.x;
  const uint32_t* gh = hist + (size_t)sid * 4096;
  __shared__ uint32_t ps[256];
  uint32_t sum = 0;
  for (int i = 0; i < 16; i++) sum += gh[threadIdx.x * 16 + i];
  ps[threadIdx.x] = sum;
  __syncthreads();
  if (threadIdx.x == 0) {
    uint32_t c = 0; int T = 0, m = 1000;
    for (int ch = 255; ch >= 0; --ch) {
      if (c + ps[ch] >= 1000u) {
        for (int t = ch * 16 + 15; t >= ch * 16; --t) {
          uint32_t hv = gh[t];
          if (c + hv >= 1000u) { T = t; m = (int)(1000u - c); break; }
          c += hv;
        }
        break;
      }
      c += ps[ch];
    }
    meta[sid * 4 + 0] = T;
    meta[sid * 4 + 1] = (int)c;
    meta[sid * 4 + 2] = m;
    meta[sid * 4 + 3] = (int)gh[T];
  }
}

// two-pass block-aggregated collect: 2 global atomics per block
__global__ __launch_bounds__(256)
void k_collect(const float* __restrict__ scores, const int* __restrict__ meta,
               unsigned long long* __restrict__ listA, unsigned long long* __restrict__ listB,
               uint32_t* __restrict__ ctrA, uint32_t* __restrict__ ctrB) {
  const int sid = blockIdx.y; const int l = sid >> 1, b = sid & 1;
  const int HW = cLHW[l]; const int size = NCLS * HW;
  const int base = blockIdx.x * 4096;
  if (base >= size) return;
  const size_t sbase = (size_t)NCLS * (2 * cLCUM[l] + b * HW);
  const float* sb = scores + sbase;
  unsigned long long* lB = listB + sbase;
  unsigned long long* lA = listA + (size_t)sid * 1024;
  const uint32_t T = (uint32_t)meta[sid * 4];
  const int lane = (int)(threadIdx.x & 63u);
  __shared__ uint32_t cA, cB, bA, bB;
  if (threadIdx.x == 0) { cA = 0; cB = 0; }
  __syncthreads();
  uint32_t wa = 0, wb = 0;
  for (int j = 0; j < 16; j++) {
    int i = base + threadIdx.x + j * 256;
    bool inb = (i < size);
    uint32_t bits = inb ? __float_as_uint(sb[i]) : 0u;
    uint32_t bkt = bits >> 20;
    unsigned long long mA = __ballot(inb && bkt > T);
    unsigned long long mB = __ballot(inb && bkt == T);
    if (lane == 0) { wa += (uint32_t)__popcll(mA); wb += (uint32_t)__popcll(mB); }
  }
  if (lane == 0) { if (wa) atomicAdd(&cA, wa); if (wb) atomicAdd(&cB, wb); }
  __syncthreads();
  if (threadIdx.x == 0) {
    bA = cA ? atomicAdd(&ctrA[sid], cA) : 0u;
    bB = cB ? atomicAdd(&ctrB[sid], cB) : 0u;
    cA = 0; cB = 0;
  }
  __syncthreads();
  for (int j = 0; j < 16; j++) {
    int i = base + threadIdx.x + j * 256;
    bool inb = (i < size);
    uint32_t bits = inb ? __float_as_uint(sb[i]) : 0u;
    uint32_t bkt = bits >> 20;
    bool pA = inb && bkt > T;
    bool pB = inb && bkt == T;
    unsigned long long key = 0;
    if (pA || pB) {
      int cls = i / HW; int hw = i - cls * HW;
      uint32_t idx = (uint32_t)(hw * NCLS + cls);
      key = ((unsigned long long)bits << 32) | (unsigned long long)(0xFFFFFFFFu - idx);
    }
    unsigned long long mA = __ballot(pA);
    unsigned long long mB = __ballot(pB);
    unsigned long long lt = (1ull << lane) - 1ull;
    if (mA) {
      int ld = __ffsll(mA) - 1;
      uint32_t wbs = 0;
      if (lane == ld) wbs = atomicAdd(&cA, (uint32_t)__popcll(mA));
      wbs = (uint32_t)__shfl((int)wbs, ld, 64);
      if (pA) {
        uint32_t pos = bA + wbs + (uint32_t)__popcll(mA & lt);
        if (pos < 1024u) lA[pos] = key;
      }
    }
    if (mB) {
      int ld = __ffsll(mB) - 1;
      uint32_t wbs = 0;
      if (lane == ld) wbs = atomicAdd(&cB, (uint32_t)__popcll(mB));
      wbs = (uint32_t)__shfl((int)wbs, ld, 64);
      if (pB) lB[bB + wbs + (uint32_t)__popcll(mB & lt)] = key;
    }
  }
}

__global__ __launch_bounds__(1024)
void k_refine(const int* __restrict__ meta, const unsigned long long* __restrict__ listB,
              unsigned long long* __restrict__ listA, uint32_t* __restrict__ ctrA) {
  const int sid = blockIdx.x; const int l = sid >> 1, b = sid & 1;
  const int HW = cLHW[l];
  const size_t sbase = (size_t)NCLS * (2 * cLCUM[l] + b * HW);
  const unsigned long long* lB = listB + sbase;
  const int nB = meta[sid * 4 + 3];
  int m = meta[sid * 4 + 2];
  __shared__ uint32_t h[256];
  __shared__ unsigned long long sPre;
  __shared__ int sM;
  __shared__ uint32_t sCnt;
  unsigned long long prefix = 0, mask = 0;
  for (int p = 7; p >= 0; --p) {
    for (int i = threadIdx.x; i < 256; i += 1024) h[i] = 0;
    __syncthreads();
    for (int i = threadIdx.x; i < nB; i += 1024) {
      unsigned long long k = lB[i];
      if ((k & mask) == prefix) {
        uint32_t bkt = (uint32_t)((k >> (p * 8)) & 255ull);
        lds_hist_add(h, bkt);
      }
    }
    __syncthreads();
    if (threadIdx.x == 0) {
      uint32_t c = 0; int sel = 0; int mnew = m;
      for (int t = 255; t >= 0; --t) {
        if (c + h[t] >= (uint32_t)m) { sel = t; mnew = m - (int)c; break; }
        c += h[t];
      }
      sPre = prefix | ((unsigned long long)sel << (p * 8));
      sM = mnew;
    }
    __syncthreads();
    prefix = sPre; m = sM;
    mask |= (0xFFull << (p * 8));
    __syncthreads();
  }
  if (threadIdx.x == 0) sCnt = ctrA[sid];
  __syncthreads();
  for (int i = threadIdx.x; i < nB; i += 1024) {
    unsigned long long k = lB[i];
    if (k >= prefix) {
      uint32_t pos = atomicAdd(&sCnt, 1u);
      if (pos < 1024u) listA[(size_t)sid * 1024 + pos] = k;
    }
  }
  __syncthreads();
  if (threadIdx.x == 0) ctrA[sid] = sCnt;
}

__global__ __launch_bounds__(256)
void k_sortdec(const unsigned long long* __restrict__ listA, const uint32_t* __restrict__ ctrA,
               const float* __restrict__ regb, float* __restrict__ cbox,
               float* __restrict__ cscr, float* __restrict__ ccls) {
  const int sid = blockIdx.x; const int l = sid >> 1, b = sid & 1;
  const int HW = cLHW[l], W = cLW[l];
  __shared__ unsigned long long key[1024];
  int n = (int)ctrA[sid]; if (n > 1024) n = 1024;
  for (int i = threadIdx.x; i < 1024; i += 256)
    key[i] = (i < n) ? listA[(size_t)sid * 1024 + i] : 0ull;
  __syncthreads();
  for (int len = 2; len <= 1024; len <<= 1) {
    for (int j = len >> 1; j > 0; j >>= 1) {
      for (int t = threadIdx.x; t < 512; t += 256) {
        int i = ((t & ~(j - 1)) << 1) | (t & (j - 1));
        int pp = i | j;
        unsigned long long a = key[i], bq = key[pp];
        bool desc = ((i & len) == 0);
        if ((a < bq) == desc) { key[i] = bq; key[pp] = a; }
      }
      __syncthreads();
    }
  }
  for (int r = threadIdx.x; r < 1000; r += 256) {
    unsigned long long k = key[r];
    uint32_t bits = (uint32_t)(k >> 32);
    uint32_t idx = 0xFFFFFFFFu - (uint32_t)(k & 0xFFFFFFFFull);
    float val = __uint_as_float(bits);
    float sc = sqrtf(fmaxf(val, 1e-12f));
    int cls = (int)(idx % NCLS); int loc = (int)(idx / NCLS);
    int hh = loc / W; int ww = loc - hh * W;
    float cx = (float)(ww * cLSTR[l] + (cLSTR[l] >> 1));
    float cy = (float)(hh * cLSTR[l] + (cLSTR[l] >> 1));
    const float* rg = regb + (size_t)(2 * cLCUM[l] + b * HW + loc) * 4;
    int slot = b * 5000 + l * 1000 + r;
    cbox[slot * 4 + 0] = cx - rg[0];
    cbox[slot * 4 + 1] = cy - rg[1];
    cbox[slot * 4 + 2] = cx + rg[2];
    cbox[slot * 4 + 3] = cy + rg[3];
    cscr[slot] = sc;
    ccls[slot] = (float)cls;
  }
}

// ---------------- NMS ----------------
__global__ __launch_bounds__(1024)
void k_nms(const float* __restrict__ cbox, const float* __restrict__ cscr,
           const float* __restrict__ ccls, float* __restrict__ out) {
  const int b = blockIdx.x;
  const int tid = threadIdx.x;
  __shared__ float s[5000];
  __shared__ float wv[16]; __shared__ int wi[16];
  __shared__ float bbx[5]; __shared__ int sBi; __shared__ float sBv;
  float x1[5], y1[5], x2[5], y2[5], ar[5];
#pragma unroll
  for (int r = 0; r < 5; r++) {
    int j = tid + r * 1024;
    if (j < 5000) {
      const float4 bx = *reinterpret_cast<const float4*>(cbox + ((size_t)b * 5000 + j) * 4);
      float off = ccls[b * 5000 + j] * 10000.0f;
      x1[r] = bx.x + off; y1[r] = bx.y + off; x2[r] = bx.z + off; y2[r] = bx.w + off;
      ar[r] = (x2[r] - x1[r]) * (y2[r] - y1[r]);
      s[j] = cscr[b * 5000 + j];
    }
  }
  __syncthreads();
  for (int it = 0; it < 100; ++it) {
    float best = -1e30f; int bi = 0x7FFFFFFF;
#pragma unroll
    for (int r = 0; r < 5; r++) {
      int j = tid + r * 1024;
      if (j < 5000) {
        float v = s[j];
        if (v > best || (v == best && j < bi)) { best = v; bi = j; }
      }
    }
    for (int o = 32; o > 0; o >>= 1) {
      float ov = __shfl_down(best, o, 64); int oi = __shfl_down(bi, o, 64);
      if (ov > best || (ov == best && oi < bi)) { best = ov; bi = oi; }
    }
    if ((tid & 63) == 0) { wv[tid >> 6] = best; wi[tid >> 6] = bi; }
    __syncthreads();
    if (tid < 64) {
      float v = (tid < 16) ? wv[tid] : -1e30f; int ix = (tid < 16) ? wi[tid] : 0x7FFFFFFF;
      for (int o = 8; o > 0; o >>= 1) {
        float ov = __shfl_down(v, o, 64); int oi = __shfl_down(ix, o, 64);
        if (ov > v || (ov == v && oi < ix)) { v = ov; ix = oi; }
      }
      if (tid == 0) { sBi = ix; sBv = v; }
    }
    __syncthreads();
    const int pick = sBi; const float pv = sBv;
    if (tid == (pick & 1023)) {
      const int r = pick >> 10;
      bbx[0] = x1[r]; bbx[1] = y1[r]; bbx[2] = x2[r]; bbx[3] = y2[r]; bbx[4] = ar[r];
      float* orow = out + ((size_t)b * 100 + it) * 6;
      if (pv > 0.f) {
        const float4 obx = *reinterpret_cast<const float4*>(cbox + ((size_t)b * 5000 + pick) * 4);
        orow[0] = obx.x; orow[1] = obx.y; orow[2] = obx.z; orow[3] = obx.w;
        orow[4] = pv; orow[5] = ccls[b * 5000 + pick];
      } else {
        orow[0] = 0.f; orow[1] = 0.f; orow[2] = 0.f; orow[3] = 0.f; orow[4] = 0.f; orow[5] = 0.f;
      }
    }
    __syncthreads();
    const float bx1 = bbx[0], by1 = bbx[1], bx2 = bbx[2], by2 = bbx[3], ba = bbx[4];
#pragma unroll
    for (int r = 0; r < 5; r++) {
      int j = tid + r * 1024;
      if (j < 5000) {
        float ix1 = fmaxf(bx1, x1[r]), iy1 = fmaxf(by1, y1[r]);
        float ix2 = fminf(bx2, x2[r]), iy2 = fminf(by2, y2[r]);
        float iw = fmaxf(ix2 - ix1, 0.f), ih = fmaxf(iy2 - iy1, 0.f);
        float inter = iw * ih;
        float iou = inter / ((ba + ar[r] - inter) + 1e-9f);
        if (iou > 0.6f || j == pick) s[j] = -1.0f;
      }
    }
    __syncthreads();
  }
}

// ---------------- host launch ----------------
static inline size_t alignup(size_t x) { return (x + 255) & ~(size_t)255; }

extern "C" void kernel_launch(void* const* d_in, const int* in_sizes, int n_in,
                              void* d_out, int out_size, void* d_ws, size_t ws_size,
                              hipStream_t stream) {
  (void)in_sizes; (void)n_in; (void)out_size; (void)ws_size;
  const float* p0 = (const float*)d_in[0];
  const float* p1 = (const float*)d_in[1];
  const float* p2 = (const float*)d_in[2];
  const float* p3 = (const float*)d_in[3];
  const float* p4 = (const float*)d_in[4];
  const float* cls_w   = (const float*)d_in[5];
  const float* cls_b   = (const float*)d_in[6];
  const float* box_w   = (const float*)d_in[7];
  const float* box_b   = (const float*)d_in[8];
  const float* logit_w = (const float*)d_in[9];
  const float* logit_b = (const float*)d_in[10];
  const float* pred_w  = (const float*)d_in[11];
  const float* pred_b  = (const float*)d_in[12];
  const float* ctr_w   = (const float*)d_in[13];
  const float* ctr_b   = (const float*)d_in[14];
  const float* scales  = (const float*)d_in[15];

  char* base = (char*)d_ws;
  size_t off = 0;
  auto take = [&](size_t bytes) { void* p = base + off; off = alignup(off + bytes); return p; };
  float* regb = (float*)take((size_t)4 * 2 * TOTHW * 4);
  float* ctrp = (float*)take((size_t)2 * TOTHW * 4);
  uint32_t* hist = (uint32_t*)take((size_t)40960 * 4);
  int* meta = (int*)take((size_t)40 * 4);
  uint32_t* ctrA = (uint32_t*)take(256);
  uint32_t* ctrB = (uint32_t*)take(256);
  unsigned long long* listA = (unsigned long long*)take((size_t)10 * 1024 * 8);
  float* cbox = (float*)take((size_t)2 * 5000 * 16);
  float* cscr = (float*)take((size_t)2 * 5000 * 4);
  float* ccls = (float*)take((size_t)2 * 5000 * 4);
  float* wh   = (float*)take((size_t)9 * 256 * 5 * 4);
  unsigned short* wpack = (unsigned short*)take((size_t)9 * 2 * 256 * 256 * 2);
  unsigned short* R1_0 = (unsigned short*)take(SBE * 2);
  unsigned short* R1_1 = (unsigned short*)take(SBE * 2);
  unsigned short* R2_0 = (unsigned short*)take(SBE * 2);
  unsigned short* R2_1 = (unsigned short*)take(SBE * 2);
  (void)take(65536);                                 // halo-read safety pad
  float* scores = (float*)R2_0;                      // free when logits conv runs
  unsigned long long* listB = (unsigned long long*)R1_0;   // spans into R1_1 (adjacent)
  float* headact = (float*)R1_0;                     // 43008*256*4 B == R1_0+R1_1 exactly

  const size_t WSTRIDE = (size_t)256 * 2304;

  hipLaunchKernelGGL(k_init, dim3(160), dim3(256), 0, stream, hist, ctrA, ctrB);
  hipLaunchKernelGGL(k_packhead, dim3(9), dim3(256), 0, stream, ctr_w, pred_w, wh);
  hipLaunchKernelGGL(k_zero, dim3(168), dim3(256), 0, stream, R1_0, R1_1);
  hipLaunchKernelGGL(k_zero, dim3(168), dim3(256), 0, stream, R2_0, R2_1);
  hipLaunchKernelGGL(k_prep, dim3(390), dim3(256), 0, stream, p0, p1, p2, p3, p4, R1_0, R1_1);

  auto runConv = [&](int epi, const unsigned short* x0, const unsigned short* x1,
                     const float* bias, unsigned short* y0, unsigned short* y1,
                     float* af, float* sc) {
    MfArgs a;
    a.X0 = x0; a.X1 = x1; a.Wp = wpack; a.bias = bias;
    a.Y0 = y0; a.Y1 = y1; a.actf = af; a.scores = sc; a.ctrp = ctrp;
    a.hist = hist;
    if (epi == 0)      hipLaunchKernelGGL(conv_mfma<0>, dim3(672), dim3(256), 0, stream, a);
    else if (epi == 1) hipLaunchKernelGGL(conv_mfma<1>, dim3(672), dim3(256), 0, stream, a);
    else               hipLaunchKernelGGL(conv_mfma<2>, dim3(336), dim3(256), 0, stream, a);
  };

  // ---- box tower ----
  hipLaunchKernelGGL(k_pack, dim3(256), dim3(256), 0, stream, box_w + 0 * WSTRIDE, wpack);
  runConv(0, R1_0, R1_1, box_b + 0,   R2_0, R2_1, nullptr, nullptr);
  hipLaunchKernelGGL(k_pack, dim3(256), dim3(256), 0, stream, box_w + 1 * WSTRIDE, wpack);
  runConv(0, R2_0, R2_1, box_b + 256, R1_0, R1_1, nullptr, nullptr);
  hipLaunchKernelGGL(k_pack, dim3(256), dim3(256), 0, stream, box_w + 2 * WSTRIDE, wpack);
  runConv(0, R1_0, R1_1, box_b + 512, R2_0, R2_1, nullptr, nullptr);
  hipLaunchKernelGGL(k_pack, dim3(256), dim3(256), 0, stream, box_w + 3 * WSTRIDE, wpack);
  runConv(1, R2_0, R2_1, box_b + 768, nullptr, nullptr, headact, nullptr);
  hipLaunchKernelGGL(k_head2, dim3(NPXB64), dim3(256), 0, stream, headact, wh, ctr_b,
                     pred_b, scales, ctrp, regb);

  // ---- cls tower (re-prep input; headact overwrote R1) ----
  hipLaunchKernelGGL(k_zero, dim3(168), dim3(256), 0, stream, R1_0, R1_1);
  hipLaunchKernelGGL(k_prep, dim3(390), dim3(256), 0, stream, p0, p1, p2, p3, p4, R1_0, R1_1);
  hipLaunchKernelGGL(k_pack, dim3(256), dim3(256), 0, stream, cls_w + 0 * WSTRIDE, wpack);
  runConv(0, R1_0, R1_1, cls_b + 0,   R2_0, R2_1, nullptr, nullptr);
  hipLaunchKernelGGL(k_pack, dim3(256), dim3(256), 0, stream, cls_w + 1 * WSTRIDE, wpack);
  runConv(0, R2_0, R2_1, cls_b + 256, R1_0, R1_1, nullptr, nullptr);
  hipLaunchKernelGGL(k_pack, dim3(256), dim3(256), 0, stream, cls_w + 2 * WSTRIDE, wpack);
  runConv(0, R1_0, R1_1, cls_b + 512, R2_0, R2_1, nullptr, nullptr);
  hipLaunchKernelGGL(k_pack, dim3(256), dim3(256), 0, stream, cls_w + 3 * WSTRIDE, wpack);
  runConv(0, R2_0, R2_1, cls_b + 768, R1_0, R1_1, nullptr, nullptr);
  hipLaunchKernelGGL(k_pack, dim3(80), dim3(256), 0, stream, logit_w, wpack);
  runConv(2, R1_0, R1_1, logit_b, nullptr, nullptr, nullptr, scores);

  // ---- top-k + decode + NMS ----
  hipLaunchKernelGGL(k_select,  dim3(10), dim3(256), 0, stream, hist, meta);
  hipLaunchKernelGGL(k_collect, dim3(297, 10), dim3(256), 0, stream, scores, meta, listA, listB, ctrA, ctrB);
  hipLaunchKernelGGL(k_refine,  dim3(10), dim3(1024), 0, stream, meta, listB, listA, ctrA);
  hipLaunchKernelGGL(k_sortdec, dim3(10), dim3(256), 0, stream, listA, ctrA, regb, cbox, cscr, ccls);
  hipLaunchKernelGGL(k_nms,     dim3(2), dim3(1024), 0, stream, cbox, cscr, ccls, (float*)d_out);
}